// Round 1
// baseline (11093.143 us; speedup 1.0000x reference)
//
#include <hip/hip_runtime.h>
#include <hip/hip_bf16.h>

// ---------------- problem constants ----------------
#define BB 8
#define TT 8
#define LL 257
#define DD 1024
#define HH 16
#define CC 64
#define SS 8
#define NTOK (BB*TT*LL)   // 16448
#define D3 (3*DD)         // 3072
#define DFF (4*DD)        // 4096

typedef unsigned short u16;   // bf16 bits

__device__ __forceinline__ float us2f(u16 u) {
    return __uint_as_float(((unsigned int)u) << 16);
}
__device__ __forceinline__ u16 f2us(float f) {
    unsigned int u = __float_as_uint(f);
    unsigned int rb = ((u >> 16) & 1u) + 0x7fffu;   // round-to-nearest-even
    return (u16)((u + rb) >> 16);
}

// ---------------- LayerNorm over last dim (1024), optional residual add ----------------
__global__ __launch_bounds__(256)
void ln_rows(const float* __restrict__ X, const float* __restrict__ R,
             const float* __restrict__ g, const float* __restrict__ bta,
             u16* __restrict__ out, int M)
{
    int row = blockIdx.x;
    if (row >= M) return;
    const float* x = X + (size_t)row * DD;
    const float* r = R ? R + (size_t)row * DD : nullptr;
    int t = threadIdx.x;
    float v[4]; float s1 = 0.f, s2 = 0.f;
#pragma unroll
    for (int i = 0; i < 4; ++i) {
        float val = x[t + 256 * i];
        if (r) val += r[t + 256 * i];
        v[i] = val; s1 += val; s2 += val * val;
    }
#pragma unroll
    for (int o = 32; o > 0; o >>= 1) { s1 += __shfl_xor(s1, o, 64); s2 += __shfl_xor(s2, o, 64); }
    __shared__ float red[10];
    int wid = t >> 6, lane = t & 63;
    if (lane == 0) { red[wid] = s1; red[4 + wid] = s2; }
    __syncthreads();
    if (t == 0) {
        float a = red[0] + red[1] + red[2] + red[3];
        float q = red[4] + red[5] + red[6] + red[7];
        float mu = a * (1.f / DD);
        float var = q * (1.f / DD) - mu * mu;
        red[8] = mu; red[9] = rsqrtf(var + 1e-5f);
    }
    __syncthreads();
    float mu = red[8], rs = red[9];
#pragma unroll
    for (int i = 0; i < 4; ++i) {
        int c = t + 256 * i;
        out[(size_t)row * DD + c] = f2us((v[i] - mu) * rs * g[c] + bta[c]);
    }
}

// ---------------- LayerNorm over whole (T,D) tensor (te) ----------------
__global__ __launch_bounds__(256)
void ln_te(const float* __restrict__ te, const float* __restrict__ g,
           const float* __restrict__ bta, u16* __restrict__ out)
{
    const int NE = TT * DD;   // 8192
    int t = threadIdx.x;
    float s1 = 0.f, s2 = 0.f;
    for (int i = t; i < NE; i += 256) { float v = te[i]; s1 += v; s2 += v * v; }
#pragma unroll
    for (int o = 32; o > 0; o >>= 1) { s1 += __shfl_xor(s1, o, 64); s2 += __shfl_xor(s2, o, 64); }
    __shared__ float red[10];
    int wid = t >> 6, lane = t & 63;
    if (lane == 0) { red[wid] = s1; red[4 + wid] = s2; }
    __syncthreads();
    if (t == 0) {
        float a = red[0] + red[1] + red[2] + red[3];
        float q = red[4] + red[5] + red[6] + red[7];
        float mu = a / (float)NE;
        float var = q / (float)NE - mu * mu;
        red[8] = mu; red[9] = rsqrtf(var + 1e-5f);
    }
    __syncthreads();
    float mu = red[8], rs = red[9];
    for (int i = t; i < NE; i += 256)
        out[i] = f2us((te[i] - mu) * rs * g[i] + bta[i]);
}

// ---------------- generic GEMM: C[m,j] = sum_k A[m,k]*W[j,k] (+bias) ----------------
// A: bf16(u16) [M,K] row-major; W: f32 [N,K] row-major (i.e. B^T layout).
enum { EPI_BF16 = 0, EPI_GELU = 1, EPI_RES = 2, EPI_F32 = 3 };

template<int EPI>
__global__ __launch_bounds__(256)
void gemm_bt(const u16* __restrict__ A, const float* __restrict__ W,
             const float* __restrict__ bias, int M, int N, int K,
             u16* __restrict__ outB, float* outF, const float* res)
{
    __shared__ float As[32][68];
    __shared__ float Ws[32][68];
    const int tid = threadIdx.x;
    const int tx = tid & 15, ty = tid >> 4;
    const int m0 = blockIdx.y * 64, n0 = blockIdx.x * 64;
    float acc[4][4] = {};
    for (int k0 = 0; k0 < K; k0 += 32) {
#pragma unroll
        for (int i = 0; i < 8; ++i) {
            int idx = tid + i * 256;
            int mm = idx >> 5, kk = idx & 31;
            float av = 0.f;
            if (m0 + mm < M) av = us2f(A[(size_t)(m0 + mm) * K + k0 + kk]);
            As[kk][mm] = av;
            Ws[kk][mm] = W[(size_t)(n0 + mm) * K + k0 + kk];
        }
        __syncthreads();
#pragma unroll
        for (int kk = 0; kk < 32; ++kk) {
            float4 a4 = *reinterpret_cast<const float4*>(&As[kk][ty * 4]);
            float4 w4 = *reinterpret_cast<const float4*>(&Ws[kk][tx * 4]);
            float a[4] = {a4.x, a4.y, a4.z, a4.w};
            float w[4] = {w4.x, w4.y, w4.z, w4.w};
#pragma unroll
            for (int i = 0; i < 4; ++i)
#pragma unroll
                for (int j = 0; j < 4; ++j)
                    acc[i][j] += a[i] * w[j];
        }
        __syncthreads();
    }
#pragma unroll
    for (int i = 0; i < 4; ++i) {
        int m = m0 + ty * 4 + i;
        if (m >= M) continue;
#pragma unroll
        for (int j = 0; j < 4; ++j) {
            int n = n0 + tx * 4 + j;
            float c = acc[i][j];
            if (bias) c += bias[n];
            size_t o = (size_t)m * N + n;
            if (EPI == EPI_BF16) outB[o] = f2us(c);
            else if (EPI == EPI_GELU) { float gg = c / (1.f + __expf(-1.702f * c)); outB[o] = f2us(gg); }
            else if (EPI == EPI_RES) outF[o] = res[o] + c;
            else outF[o] = c;
        }
    }
}

// ---------------- spatial attention: one block per (h, b*t) ----------------
// q,k,v packed in qkv [NTOK, 3072] bf16; out mix [NTOK, 1024] bf16.
__global__ __launch_bounds__(256)
void spatial_attn(const u16* __restrict__ qkv, u16* __restrict__ mix)
{
    const int h = blockIdx.x, bt = blockIdx.y;
    const int hoff = h * CC;
    const size_t base = (size_t)bt * LL * D3;
    __shared__ u16 Kls[LL * 66];
    __shared__ float pls[4][LL];
    const int tid = threadIdx.x, lane = tid & 63, w = tid >> 6;

    for (int idx = tid; idx < LL * CC; idx += 256) {
        int key = idx >> 6, c = idx & 63;
        Kls[key * 66 + c] = qkv[base + (size_t)key * D3 + DD + hoff + c];
    }
    __syncthreads();

    const u16* vg = qkv + base + 2 * DD + hoff + lane;   // V column for this lane
    for (int r = w; r < LL; r += 4) {
        float qc = us2f(qkv[base + (size_t)r * D3 + hoff + lane]) * 0.125f;
        float sc[5];
#pragma unroll
        for (int j = 0; j < 5; ++j) sc[j] = 0.f;
        for (int c = 0; c < CC; ++c) {
            float qv = __shfl(qc, c, 64);
#pragma unroll
            for (int j = 0; j < 4; ++j)
                sc[j] += qv * us2f(Kls[(lane + 64 * j) * 66 + c]);
            sc[4] += qv * us2f(Kls[256 * 66 + c]);   // same value on all lanes (key 256)
        }
        float mx = fmaxf(fmaxf(fmaxf(sc[0], sc[1]), fmaxf(sc[2], sc[3])), sc[4]);
#pragma unroll
        for (int o = 32; o > 0; o >>= 1) mx = fmaxf(mx, __shfl_xor(mx, o, 64));
        float sum = 0.f;
#pragma unroll
        for (int j = 0; j < 5; ++j) sc[j] = __expf(sc[j] - mx);
        sum = sc[0] + sc[1] + sc[2] + sc[3] + (lane == 0 ? sc[4] : 0.f);
#pragma unroll
        for (int o = 32; o > 0; o >>= 1) sum += __shfl_xor(sum, o, 64);
        float inv = 1.f / sum;
#pragma unroll
        for (int j = 0; j < 4; ++j) pls[w][lane + 64 * j] = sc[j] * inv;
        if (lane == 0) pls[w][256] = sc[4] * inv;
        // PV: lane = channel c; V read from global (coalesced, L2-hot)
        float acc = 0.f;
        for (int key = 0; key < LL; ++key)
            acc += pls[w][key] * us2f(vg[(size_t)key * D3]);
        mix[((size_t)bt * LL + r) * DD + hoff + lane] = f2us(acc);
    }
}

// ---------------- syno-token attention: one block (1 wave) per (h, b*t) ----------------
__global__ __launch_bounds__(64)
void s_attn(const u16* __restrict__ qkv, const u16* __restrict__ snqkv,
            const u16* __restrict__ teqkv, const float* __restrict__ pmask,
            float* __restrict__ smix)
{
    const int h = blockIdx.x, bt = blockIdx.y, b = bt >> 3, t = bt & 7;
    const int hoff = h * CC, lane = threadIdx.x;
    __shared__ u16 Kls[256 * 66];
    __shared__ float pls[256];
    const size_t base = (size_t)bt * LL * D3;
    const float tek = us2f(teqkv[t * D3 + DD + hoff + lane]);
    const float tev = us2f(teqkv[t * D3 + 2 * DD + hoff + lane]);
    for (int key = 0; key < 256; ++key) {   // lane = channel
        float kv = us2f(qkv[base + (size_t)(key + 1) * D3 + DD + hoff + lane]) + tek;
        Kls[key * 66 + lane] = f2us(kv);
    }
    const float* pm = pmask + (size_t)bt * 256;
    const u16* vgl = qkv + base + 2 * DD + hoff + lane;
    for (int q = 0; q < SS; ++q) {
        float qc = us2f(snqkv[((size_t)(b * SS + q)) * D3 + hoff + lane]) * 0.125f;
        float sc[4] = {0.f, 0.f, 0.f, 0.f};
        for (int c = 0; c < CC; ++c) {
            float qv = __shfl(qc, c, 64);
#pragma unroll
            for (int j = 0; j < 4; ++j)
                sc[j] += qv * us2f(Kls[(lane + 64 * j) * 66 + c]);
        }
#pragma unroll
        for (int j = 0; j < 4; ++j) sc[j] += pm[lane + 64 * j];
        float mx = fmaxf(fmaxf(sc[0], sc[1]), fmaxf(sc[2], sc[3]));
#pragma unroll
        for (int o = 32; o > 0; o >>= 1) mx = fmaxf(mx, __shfl_xor(mx, o, 64));
        float sum = 0.f;
#pragma unroll
        for (int j = 0; j < 4; ++j) { sc[j] = __expf(sc[j] - mx); sum += sc[j]; }
#pragma unroll
        for (int o = 32; o > 0; o >>= 1) sum += __shfl_xor(sum, o, 64);
        float inv = 1.f / sum;
#pragma unroll
        for (int j = 0; j < 4; ++j) pls[lane + 64 * j] = sc[j] * inv;
        float acc = 0.f;
        for (int key = 0; key < 256; ++key)
            acc += pls[key] * (us2f(vgl[(size_t)(key + 1) * D3]) + tev);
        smix[(((size_t)bt * SS + q) * HH + h) * CC + lane] = acc;
    }
}

// ---------------- depthwise temporal conv (k=3,pad=1) + residual + mean over T ----------------
__global__ __launch_bounds__(256)
void conv_mean(const float* __restrict__ smix, const float* __restrict__ cw,
               const float* __restrict__ cb, u16* __restrict__ out)
{
    int idx = blockIdx.x * 256 + threadIdx.x;    // (b,s,d): 65536 total
    int d = idx & 1023;
    int bs = idx >> 10;
    int b = bs >> 3, s_ = bs & 7;
    float z[TT];
#pragma unroll
    for (int t = 0; t < TT; ++t)
        z[t] = smix[((size_t)(b * TT + t) * SS + s_) * DD + d];
    float w0 = cw[d * 3], w1 = cw[d * 3 + 1], w2 = cw[d * 3 + 2];
    float acc = 0.f;
#pragma unroll
    for (int t = 0; t < TT; ++t) {
        float zc = w1 * z[t];
        if (t > 0)      zc += w0 * z[t - 1];
        if (t < TT - 1) zc += w2 * z[t + 1];
        acc += z[t] + zc;
    }
    out[(size_t)bs * DD + d] = f2us(acc * 0.125f + cb[d]);
}

// ---------------- host: launch sequence ----------------
extern "C" void kernel_launch(void* const* d_in, const int* in_sizes, int n_in,
                              void* d_out, int out_size, void* d_ws, size_t ws_size,
                              hipStream_t stream)
{
    const float* x      = (const float*)d_in[0];
    const float* s      = (const float*)d_in[1];
    const float* te     = (const float*)d_in[2];
    const float* pmask  = (const float*)d_in[3];
    const float* in_w   = (const float*)d_in[4];
    const float* in_b   = (const float*)d_in[5];
    const float* out_w  = (const float*)d_in[6];
    const float* out_b  = (const float*)d_in[7];
    const float* ln1_g  = (const float*)d_in[8];
    const float* ln1_b  = (const float*)d_in[9];
    const float* ln2_g  = (const float*)d_in[10];
    const float* ln2_b  = (const float*)d_in[11];
    const float* fc_w   = (const float*)d_in[12];
    const float* fc_b   = (const float*)d_in[13];
    const float* proj_w = (const float*)d_in[14];
    const float* proj_b = (const float*)d_in[15];
    const float* smlp_g = (const float*)d_in[16];
    const float* smlp_b = (const float*)d_in[17];
    const float* w1     = (const float*)d_in[18];
    const float* w2     = (const float*)d_in[19];
    const float* lnte_g = (const float*)d_in[20];
    const float* lnte_b = (const float*)d_in[21];
    const float* conv_w = (const float*)d_in[22];
    const float* conv_b = (const float*)d_in[23];

    float* outx = (float*)d_out;                     // [NTOK, 1024]
    float* outs = outx + (size_t)NTOK * DD;          // [64, 1024]

    char* ws = (char*)d_ws;
    u16* qkv    = (u16*)ws;                                      // [NTOK,3072] bf16
    u16* mixb   = (u16*)(ws + (size_t)NTOK * D3 * 2);            // [NTOK,1024] bf16
    u16* hidden = qkv;                                           // [NTOK,4096] overlay (exact)
    u16* xn     = (u16*)(ws + (size_t)NTOK * DFF * 2);           // [NTOK,1024] bf16
    char* sm    = ws + (size_t)NTOK * DFF * 2 + (size_t)NTOK * DD * 2;
    u16*  s_ln0 = (u16*)sm;   sm += 64 * DD * 2;
    u16*  h1    = (u16*)sm;   sm += 64 * 128 * 2;
    float* smlp = (float*)sm; sm += 64 * DD * 4;
    u16*  sn    = (u16*)sm;   sm += 64 * DD * 2;
    u16*  snqkv = (u16*)sm;   sm += 64 * D3 * 2;
    u16*  ten   = (u16*)sm;   sm += 8 * DD * 2;
    u16*  teqkv = (u16*)sm;   sm += 8 * D3 * 2;
    float* smix = (float*)sm; sm += (size_t)BB * TT * SS * DD * 4;
    u16*  smm   = (u16*)sm;   sm += 64 * DD * 2;
    u16*  ln2s  = (u16*)sm;   sm += 64 * DD * 2;
    u16*  hids  = (u16*)sm;   sm += 64 * DFF * 2;

    const float* FNULL = nullptr;
    u16* UNULL = nullptr;

    // 1. xn = LN1(x)
    hipLaunchKernelGGL(ln_rows, dim3(NTOK), dim3(256), 0, stream, x, FNULL, ln1_g, ln1_b, xn, NTOK);
    // 2. qkv = xn @ in_proj_w^T + b
    hipLaunchKernelGGL((gemm_bt<EPI_BF16>), dim3(D3 / 64, NTOK / 64), dim3(256), 0, stream,
                       xn, in_w, in_b, NTOK, D3, DD, qkv, (float*)nullptr, FNULL);
    // 3. spatial attention -> mix
    hipLaunchKernelGGL(spatial_attn, dim3(HH, BB * TT), dim3(256), 0, stream, qkv, mixb);
    // 4. outx = x + mix @ out_w^T + out_b
    hipLaunchKernelGGL((gemm_bt<EPI_RES>), dim3(DD / 64, NTOK / 64), dim3(256), 0, stream,
                       mixb, out_w, out_b, NTOK, DD, DD, UNULL, outx, x);
    // 5. syno-token branch
    hipLaunchKernelGGL(ln_rows, dim3(64), dim3(256), 0, stream, s, FNULL, smlp_g, smlp_b, s_ln0, 64);
    hipLaunchKernelGGL((gemm_bt<EPI_BF16>), dim3(128 / 64, 1), dim3(256), 0, stream,
                       s_ln0, w1, FNULL, 64, 128, DD, h1, (float*)nullptr, FNULL);
    hipLaunchKernelGGL((gemm_bt<EPI_F32>), dim3(DD / 64, 1), dim3(256), 0, stream,
                       h1, w2, FNULL, 64, DD, 128, UNULL, smlp, FNULL);
    hipLaunchKernelGGL(ln_rows, dim3(64), dim3(256), 0, stream, s, smlp, ln1_g, ln1_b, sn, 64);
    hipLaunchKernelGGL(ln_te, dim3(1), dim3(256), 0, stream, te, lnte_g, lnte_b, ten);
    hipLaunchKernelGGL((gemm_bt<EPI_BF16>), dim3(D3 / 64, 1), dim3(256), 0, stream,
                       sn, in_w, in_b, 64, D3, DD, snqkv, (float*)nullptr, FNULL);
    hipLaunchKernelGGL((gemm_bt<EPI_BF16>), dim3(D3 / 64, 1), dim3(256), 0, stream,
                       ten, in_w, in_b, 8, D3, DD, teqkv, (float*)nullptr, FNULL);
    hipLaunchKernelGGL(s_attn, dim3(HH, BB * TT), dim3(64), 0, stream, qkv, snqkv, teqkv, pmask, smix);
    hipLaunchKernelGGL(conv_mean, dim3(256), dim3(256), 0, stream, smix, conv_w, conv_b, smm);
    hipLaunchKernelGGL((gemm_bt<EPI_RES>), dim3(DD / 64, 1), dim3(256), 0, stream,
                       smm, out_w, out_b, 64, DD, DD, UNULL, outs, s);
    // 6. x MLP: outx += proj(gelu(fc(LN2(outx))))
    hipLaunchKernelGGL(ln_rows, dim3(NTOK), dim3(256), 0, stream, outx, FNULL, ln2_g, ln2_b, xn, NTOK);
    hipLaunchKernelGGL((gemm_bt<EPI_GELU>), dim3(DFF / 64, NTOK / 64), dim3(256), 0, stream,
                       xn, fc_w, fc_b, NTOK, DFF, DD, hidden, (float*)nullptr, FNULL);
    hipLaunchKernelGGL((gemm_bt<EPI_RES>), dim3(DD / 64, NTOK / 64), dim3(256), 0, stream,
                       hidden, proj_w, proj_b, NTOK, DD, DFF, UNULL, outx, outx);
    // 7. s MLP
    hipLaunchKernelGGL(ln_rows, dim3(64), dim3(256), 0, stream, outs, FNULL, ln2_g, ln2_b, ln2s, 64);
    hipLaunchKernelGGL((gemm_bt<EPI_GELU>), dim3(DFF / 64, 1), dim3(256), 0, stream,
                       ln2s, fc_w, fc_b, 64, DFF, DD, hids, (float*)nullptr, FNULL);
    hipLaunchKernelGGL((gemm_bt<EPI_RES>), dim3(DD / 64, 1), dim3(256), 0, stream,
                       hids, proj_w, proj_b, 64, DD, DFF, UNULL, outs, outs);
}

// Round 2
// 3842.542 us; speedup vs baseline: 2.8869x; 2.8869x over previous
//
#include <hip/hip_runtime.h>
#include <hip/hip_bf16.h>

// ---------------- problem constants ----------------
#define BB 8
#define TT 8
#define LL 257
#define DD 1024
#define HH 16
#define CC 64
#define SS 8
#define NTOK (BB*TT*LL)   // 16448
#define D3 (3*DD)         // 3072
#define DFF (4*DD)        // 4096

typedef unsigned short u16;   // bf16 bits
typedef __attribute__((ext_vector_type(8))) short short8;
typedef __attribute__((ext_vector_type(4))) float f32x4;

__device__ __forceinline__ float us2f(u16 u) {
    return __uint_as_float(((unsigned int)u) << 16);
}
__device__ __forceinline__ u16 f2us(float f) {
    unsigned int u = __float_as_uint(f);
    unsigned int rb = ((u >> 16) & 1u) + 0x7fffu;   // round-to-nearest-even
    return (u16)((u + rb) >> 16);
}

__device__ __forceinline__ void gload_lds16(const u16* g, u16* l) {
    __builtin_amdgcn_global_load_lds(
        (__attribute__((address_space(1))) void*)(void*)g,
        (__attribute__((address_space(3))) void*)(void*)l, 16, 0, 0);
}

// ---------------- fp32 -> bf16 weight conversion ----------------
__global__ __launch_bounds__(256)
void cvt_w(const float* __restrict__ in, u16* __restrict__ out, int n4)
{
    int i = blockIdx.x * 256 + threadIdx.x;
    if (i >= n4) return;
    float4 v = reinterpret_cast<const float4*>(in)[i];
    ushort4 o;
    o.x = f2us(v.x); o.y = f2us(v.y); o.z = f2us(v.z); o.w = f2us(v.w);
    reinterpret_cast<ushort4*>(out)[i] = o;
}

// ---------------- LayerNorm over last dim (1024), optional residual add ----------------
__global__ __launch_bounds__(256)
void ln_rows(const float* __restrict__ X, const float* __restrict__ R,
             const float* __restrict__ g, const float* __restrict__ bta,
             u16* __restrict__ out, int M)
{
    int row = blockIdx.x;
    if (row >= M) return;
    const float* x = X + (size_t)row * DD;
    const float* r = R ? R + (size_t)row * DD : nullptr;
    int t = threadIdx.x;
    float v[4]; float s1 = 0.f, s2 = 0.f;
#pragma unroll
    for (int i = 0; i < 4; ++i) {
        float val = x[t + 256 * i];
        if (r) val += r[t + 256 * i];
        v[i] = val; s1 += val; s2 += val * val;
    }
#pragma unroll
    for (int o = 32; o > 0; o >>= 1) { s1 += __shfl_xor(s1, o, 64); s2 += __shfl_xor(s2, o, 64); }
    __shared__ float red[10];
    int wid = t >> 6, lane = t & 63;
    if (lane == 0) { red[wid] = s1; red[4 + wid] = s2; }
    __syncthreads();
    if (t == 0) {
        float a = red[0] + red[1] + red[2] + red[3];
        float q = red[4] + red[5] + red[6] + red[7];
        float mu = a * (1.f / DD);
        float var = q * (1.f / DD) - mu * mu;
        red[8] = mu; red[9] = rsqrtf(var + 1e-5f);
    }
    __syncthreads();
    float mu = red[8], rs = red[9];
#pragma unroll
    for (int i = 0; i < 4; ++i) {
        int c = t + 256 * i;
        out[(size_t)row * DD + c] = f2us((v[i] - mu) * rs * g[c] + bta[c]);
    }
}

// ---------------- LayerNorm over whole (T,D) tensor (te) ----------------
__global__ __launch_bounds__(256)
void ln_te(const float* __restrict__ te, const float* __restrict__ g,
           const float* __restrict__ bta, u16* __restrict__ out)
{
    const int NE = TT * DD;   // 8192
    int t = threadIdx.x;
    float s1 = 0.f, s2 = 0.f;
    for (int i = t; i < NE; i += 256) { float v = te[i]; s1 += v; s2 += v * v; }
#pragma unroll
    for (int o = 32; o > 0; o >>= 1) { s1 += __shfl_xor(s1, o, 64); s2 += __shfl_xor(s2, o, 64); }
    __shared__ float red[10];
    int wid = t >> 6, lane = t & 63;
    if (lane == 0) { red[wid] = s1; red[4 + wid] = s2; }
    __syncthreads();
    if (t == 0) {
        float a = red[0] + red[1] + red[2] + red[3];
        float q = red[4] + red[5] + red[6] + red[7];
        float mu = a / (float)NE;
        float var = q / (float)NE - mu * mu;
        red[8] = mu; red[9] = rsqrtf(var + 1e-5f);
    }
    __syncthreads();
    float mu = red[8], rs = red[9];
    for (int i = t; i < NE; i += 256)
        out[i] = f2us((te[i] - mu) * rs * g[i] + bta[i]);
}

// ---------------- MFMA GEMM: C[m,j] = sum_k A[m,k]*W[j,k] (+bias) ----------------
// A: bf16 [M,K] row-major; W: bf16 [N,K] row-major (B^T layout). K%32==0, N%128==0.
// 128x128 tile, BK=32, 4 waves (2x2), each wave 64x64 via 4x4 mfma_16x16x32 frags.
// LDS layout: per 16-row group, 64 slots of 16B ordered slot = kb*16 + row_in_group,
// so a wave's fragment ds_read is base + lane*16 (conflict-free) and staging is
// linear in lane order (global_load_lds requirement); the permutation lives in the
// per-lane GLOBAL source address.
enum { EPI_BF16 = 0, EPI_GELU = 1, EPI_RES = 2, EPI_F32 = 3 };

template<int EPI>
__global__ __launch_bounds__(256)
void gemm_mfma(const u16* __restrict__ A, const u16* __restrict__ W,
               const float* __restrict__ bias, int M, int N, int K,
               u16* __restrict__ outB, float* __restrict__ outF,
               const float* __restrict__ res)
{
    __shared__ u16 Als[128 * 32];
    __shared__ u16 Bls[128 * 32];
    const int tid = threadIdx.x;
    const int lane = tid & 63;
    const int wid = tid >> 6;
    const int wm = (wid >> 1) * 64, wn = (wid & 1) * 64;
    const int m0 = blockIdx.y * 128, n0 = blockIdx.x * 128;

    // staging decomposition for this thread: two 16B slots per array per K-step
    int o0 = tid, o1 = tid + 256;
    int g0 = o0 >> 6, kb0 = (o0 >> 4) & 3, r0 = o0 & 15;
    int g1 = o1 >> 6, kb1 = (o1 >> 4) & 3, r1 = o1 & 15;
    int ar0 = m0 + g0 * 16 + r0; if (ar0 >= M) ar0 = M - 1;
    int ar1 = m0 + g1 * 16 + r1; if (ar1 >= M) ar1 = M - 1;
    int br0 = n0 + g0 * 16 + r0;
    int br1 = n0 + g1 * 16 + r1;
    const u16* a0 = A + (size_t)ar0 * K + kb0 * 8;
    const u16* a1 = A + (size_t)ar1 * K + kb1 * 8;
    const u16* b0 = W + (size_t)br0 * K + kb0 * 8;
    const u16* b1 = W + (size_t)br1 * K + kb1 * 8;

    f32x4 acc[4][4];
#pragma unroll
    for (int i = 0; i < 4; ++i)
#pragma unroll
        for (int j = 0; j < 4; ++j)
            acc[i][j] = (f32x4){0.f, 0.f, 0.f, 0.f};

    for (int k0 = 0; k0 < K; k0 += 32) {
        gload_lds16(a0 + k0, &Als[o0 * 8]);
        gload_lds16(a1 + k0, &Als[o1 * 8]);
        gload_lds16(b0 + k0, &Bls[o0 * 8]);
        gload_lds16(b1 + k0, &Bls[o1 * 8]);
        __syncthreads();
        short8 af[4], bfr[4];
#pragma unroll
        for (int i = 0; i < 4; ++i)
            af[i] = *reinterpret_cast<const short8*>(&Als[((wm >> 4) + i) * 512 + lane * 8]);
#pragma unroll
        for (int j = 0; j < 4; ++j)
            bfr[j] = *reinterpret_cast<const short8*>(&Bls[((wn >> 4) + j) * 512 + lane * 8]);
#pragma unroll
        for (int i = 0; i < 4; ++i)
#pragma unroll
            for (int j = 0; j < 4; ++j)
                acc[i][j] = __builtin_amdgcn_mfma_f32_16x16x32_bf16(af[i], bfr[j], acc[i][j], 0, 0, 0);
        __syncthreads();
    }

    // epilogue: C/D layout col=lane&15, row=(lane>>4)*4+reg  [m89]
    const int cn = lane & 15, cr = (lane >> 4) * 4;
#pragma unroll
    for (int i = 0; i < 4; ++i) {
#pragma unroll
        for (int r = 0; r < 4; ++r) {
            int m = m0 + wm + i * 16 + cr + r;
            if (m >= M) continue;
#pragma unroll
            for (int j = 0; j < 4; ++j) {
                int n = n0 + wn + j * 16 + cn;
                float c = acc[i][j][r];
                if (bias) c += bias[n];
                size_t o = (size_t)m * N + n;
                if (EPI == EPI_BF16) outB[o] = f2us(c);
                else if (EPI == EPI_GELU) { float gg = c / (1.f + __expf(-1.702f * c)); outB[o] = f2us(gg); }
                else if (EPI == EPI_RES) outF[o] = res[o] + c;
                else outF[o] = c;
            }
        }
    }
}

// ---------------- spatial attention: one block per (h, b*t) ----------------
__global__ __launch_bounds__(256)
void spatial_attn(const u16* __restrict__ qkv, u16* __restrict__ mix)
{
    const int h = blockIdx.x, bt = blockIdx.y;
    const int hoff = h * CC;
    const size_t base = (size_t)bt * LL * D3;
    __shared__ u16 Kls[LL * 66];
    __shared__ float pls[4][LL];
    const int tid = threadIdx.x, lane = tid & 63, w = tid >> 6;

    for (int idx = tid; idx < LL * CC; idx += 256) {
        int key = idx >> 6, c = idx & 63;
        Kls[key * 66 + c] = qkv[base + (size_t)key * D3 + DD + hoff + c];
    }
    __syncthreads();

    const u16* vg = qkv + base + 2 * DD + hoff + lane;   // V column for this lane
    for (int r = w; r < LL; r += 4) {
        float qc = us2f(qkv[base + (size_t)r * D3 + hoff + lane]) * 0.125f;
        float sc[5];
#pragma unroll
        for (int j = 0; j < 5; ++j) sc[j] = 0.f;
        for (int c = 0; c < CC; ++c) {
            float qv = __shfl(qc, c, 64);
#pragma unroll
            for (int j = 0; j < 4; ++j)
                sc[j] += qv * us2f(Kls[(lane + 64 * j) * 66 + c]);
            sc[4] += qv * us2f(Kls[256 * 66 + c]);
        }
        float mx = fmaxf(fmaxf(fmaxf(sc[0], sc[1]), fmaxf(sc[2], sc[3])), sc[4]);
#pragma unroll
        for (int o = 32; o > 0; o >>= 1) mx = fmaxf(mx, __shfl_xor(mx, o, 64));
        float sum = 0.f;
#pragma unroll
        for (int j = 0; j < 5; ++j) sc[j] = __expf(sc[j] - mx);
        sum = sc[0] + sc[1] + sc[2] + sc[3] + (lane == 0 ? sc[4] : 0.f);
#pragma unroll
        for (int o = 32; o > 0; o >>= 1) sum += __shfl_xor(sum, o, 64);
        float inv = 1.f / sum;
#pragma unroll
        for (int j = 0; j < 4; ++j) pls[w][lane + 64 * j] = sc[j] * inv;
        if (lane == 0) pls[w][256] = sc[4] * inv;
        float acc = 0.f;
        for (int key = 0; key < LL; ++key)
            acc += pls[w][key] * us2f(vg[(size_t)key * D3]);
        mix[((size_t)bt * LL + r) * DD + hoff + lane] = f2us(acc);
    }
}

// ---------------- syno-token attention: one block (1 wave) per (h, b*t) ----------------
__global__ __launch_bounds__(64)
void s_attn(const u16* __restrict__ qkv, const u16* __restrict__ snqkv,
            const u16* __restrict__ teqkv, const float* __restrict__ pmask,
            float* __restrict__ smix)
{
    const int h = blockIdx.x, bt = blockIdx.y, b = bt >> 3, t = bt & 7;
    const int hoff = h * CC, lane = threadIdx.x;
    __shared__ u16 Kls[256 * 66];
    __shared__ float pls[256];
    const size_t base = (size_t)bt * LL * D3;
    const float tek = us2f(teqkv[t * D3 + DD + hoff + lane]);
    const float tev = us2f(teqkv[t * D3 + 2 * DD + hoff + lane]);
    for (int key = 0; key < 256; ++key) {
        float kv = us2f(qkv[base + (size_t)(key + 1) * D3 + DD + hoff + lane]) + tek;
        Kls[key * 66 + lane] = f2us(kv);
    }
    const float* pm = pmask + (size_t)bt * 256;
    const u16* vgl = qkv + base + 2 * DD + hoff + lane;
    for (int q = 0; q < SS; ++q) {
        float qc = us2f(snqkv[((size_t)(b * SS + q)) * D3 + hoff + lane]) * 0.125f;
        float sc[4] = {0.f, 0.f, 0.f, 0.f};
        for (int c = 0; c < CC; ++c) {
            float qv = __shfl(qc, c, 64);
#pragma unroll
            for (int j = 0; j < 4; ++j)
                sc[j] += qv * us2f(Kls[(lane + 64 * j) * 66 + c]);
        }
#pragma unroll
        for (int j = 0; j < 4; ++j) sc[j] += pm[lane + 64 * j];
        float mx = fmaxf(fmaxf(sc[0], sc[1]), fmaxf(sc[2], sc[3]));
#pragma unroll
        for (int o = 32; o > 0; o >>= 1) mx = fmaxf(mx, __shfl_xor(mx, o, 64));
        float sum = 0.f;
#pragma unroll
        for (int j = 0; j < 4; ++j) { sc[j] = __expf(sc[j] - mx); sum += sc[j]; }
#pragma unroll
        for (int o = 32; o > 0; o >>= 1) sum += __shfl_xor(sum, o, 64);
        float inv = 1.f / sum;
#pragma unroll
        for (int j = 0; j < 4; ++j) pls[lane + 64 * j] = sc[j] * inv;
        float acc = 0.f;
        for (int key = 0; key < 256; ++key)
            acc += pls[key] * (us2f(vgl[(size_t)(key + 1) * D3]) + tev);
        smix[(((size_t)bt * SS + q) * HH + h) * CC + lane] = acc;
    }
}

// ---------------- depthwise temporal conv + residual + mean over T ----------------
__global__ __launch_bounds__(256)
void conv_mean(const float* __restrict__ smix, const float* __restrict__ cw,
               const float* __restrict__ cb, u16* __restrict__ out)
{
    int idx = blockIdx.x * 256 + threadIdx.x;
    int d = idx & 1023;
    int bs = idx >> 10;
    int b = bs >> 3, s_ = bs & 7;
    float z[TT];
#pragma unroll
    for (int t = 0; t < TT; ++t)
        z[t] = smix[((size_t)(b * TT + t) * SS + s_) * DD + d];
    float w0 = cw[d * 3], w1 = cw[d * 3 + 1], w2 = cw[d * 3 + 2];
    float acc = 0.f;
#pragma unroll
    for (int t = 0; t < TT; ++t) {
        float zc = w1 * z[t];
        if (t > 0)      zc += w0 * z[t - 1];
        if (t < TT - 1) zc += w2 * z[t + 1];
        acc += z[t] + zc;
    }
    out[(size_t)bs * DD + d] = f2us(acc * 0.125f + cb[d]);
}

// ---------------- host: launch sequence ----------------
extern "C" void kernel_launch(void* const* d_in, const int* in_sizes, int n_in,
                              void* d_out, int out_size, void* d_ws, size_t ws_size,
                              hipStream_t stream)
{
    const float* x      = (const float*)d_in[0];
    const float* s      = (const float*)d_in[1];
    const float* te     = (const float*)d_in[2];
    const float* pmask  = (const float*)d_in[3];
    const float* in_w   = (const float*)d_in[4];
    const float* in_b   = (const float*)d_in[5];
    const float* out_w  = (const float*)d_in[6];
    const float* out_b  = (const float*)d_in[7];
    const float* ln1_g  = (const float*)d_in[8];
    const float* ln1_b  = (const float*)d_in[9];
    const float* ln2_g  = (const float*)d_in[10];
    const float* ln2_b  = (const float*)d_in[11];
    const float* fc_w   = (const float*)d_in[12];
    const float* fc_b   = (const float*)d_in[13];
    const float* proj_w = (const float*)d_in[14];
    const float* proj_b = (const float*)d_in[15];
    const float* smlp_g = (const float*)d_in[16];
    const float* smlp_b = (const float*)d_in[17];
    const float* w1     = (const float*)d_in[18];
    const float* w2     = (const float*)d_in[19];
    const float* lnte_g = (const float*)d_in[20];
    const float* lnte_b = (const float*)d_in[21];
    const float* conv_w = (const float*)d_in[22];
    const float* conv_b = (const float*)d_in[23];

    float* outx = (float*)d_out;                     // [NTOK, 1024]
    float* outs = outx + (size_t)NTOK * DD;          // [64, 1024]

    char* ws = (char*)d_ws;
    u16* qkv    = (u16*)ws;                                      // [NTOK,3072] bf16
    u16* mixb   = (u16*)(ws + (size_t)NTOK * D3 * 2);            // [NTOK,1024] bf16
    u16* hidden = qkv;                                           // [NTOK,4096] overlay (exact)
    u16* xn     = (u16*)(ws + (size_t)NTOK * DFF * 2);           // [NTOK,1024] bf16
    char* sm    = ws + (size_t)NTOK * DFF * 2 + (size_t)NTOK * DD * 2;
    u16*  s_ln0 = (u16*)sm;   sm += 64 * DD * 2;
    u16*  h1    = (u16*)sm;   sm += 64 * 128 * 2;
    float* smlp = (float*)sm; sm += 64 * DD * 4;
    u16*  sn    = (u16*)sm;   sm += 64 * DD * 2;
    u16*  snqkv = (u16*)sm;   sm += 64 * D3 * 2;
    u16*  ten   = (u16*)sm;   sm += 8 * DD * 2;
    u16*  teqkv = (u16*)sm;   sm += 8 * D3 * 2;
    float* smix = (float*)sm; sm += (size_t)BB * TT * SS * DD * 4;
    u16*  smm   = (u16*)sm;   sm += 64 * DD * 2;
    u16*  ln2s  = (u16*)sm;   sm += 64 * DD * 2;
    u16*  hids  = (u16*)sm;   sm += 64 * DFF * 2;
    // bf16 weights
    u16* in_wb   = (u16*)sm;  sm += (size_t)D3 * DD * 2;
    u16* out_wb  = (u16*)sm;  sm += (size_t)DD * DD * 2;
    u16* fc_wb   = (u16*)sm;  sm += (size_t)DFF * DD * 2;
    u16* proj_wb = (u16*)sm;  sm += (size_t)DD * DFF * 2;
    u16* w1b     = (u16*)sm;  sm += (size_t)128 * DD * 2;
    u16* w2b     = (u16*)sm;  sm += (size_t)DD * 128 * 2;

    const float* FNULL = nullptr;
    u16* UNULL = nullptr;

    // 0. weight conversions
    auto cvt = [&](const float* src, u16* dst, int n) {
        hipLaunchKernelGGL(cvt_w, dim3((n / 4 + 255) / 256), dim3(256), 0, stream, src, dst, n / 4);
    };
    cvt(in_w,   in_wb,   D3 * DD);
    cvt(out_w,  out_wb,  DD * DD);
    cvt(fc_w,   fc_wb,   DFF * DD);
    cvt(proj_w, proj_wb, DD * DFF);
    cvt(w1,     w1b,     128 * DD);
    cvt(w2,     w2b,     DD * 128);

    // 1. xn = LN1(x)
    hipLaunchKernelGGL(ln_rows, dim3(NTOK), dim3(256), 0, stream, x, FNULL, ln1_g, ln1_b, xn, NTOK);
    // 2. qkv = xn @ in_proj_w^T + b
    hipLaunchKernelGGL((gemm_mfma<EPI_BF16>), dim3(D3 / 128, (NTOK + 127) / 128), dim3(256), 0, stream,
                       xn, in_wb, in_b, NTOK, D3, DD, qkv, (float*)nullptr, FNULL);
    // 3. spatial attention -> mix
    hipLaunchKernelGGL(spatial_attn, dim3(HH, BB * TT), dim3(256), 0, stream, qkv, mixb);
    // 4. outx = x + mix @ out_w^T + out_b
    hipLaunchKernelGGL((gemm_mfma<EPI_RES>), dim3(DD / 128, (NTOK + 127) / 128), dim3(256), 0, stream,
                       mixb, out_wb, out_b, NTOK, DD, DD, UNULL, outx, x);
    // 5. syno-token branch
    hipLaunchKernelGGL(ln_rows, dim3(64), dim3(256), 0, stream, s, FNULL, smlp_g, smlp_b, s_ln0, 64);
    hipLaunchKernelGGL((gemm_mfma<EPI_BF16>), dim3(1, 1), dim3(256), 0, stream,
                       s_ln0, w1b, FNULL, 64, 128, DD, h1, (float*)nullptr, FNULL);
    hipLaunchKernelGGL((gemm_mfma<EPI_F32>), dim3(DD / 128, 1), dim3(256), 0, stream,
                       h1, w2b, FNULL, 64, DD, 128, UNULL, smlp, FNULL);
    hipLaunchKernelGGL(ln_rows, dim3(64), dim3(256), 0, stream, s, smlp, ln1_g, ln1_b, sn, 64);
    hipLaunchKernelGGL(ln_te, dim3(1), dim3(256), 0, stream, te, lnte_g, lnte_b, ten);
    hipLaunchKernelGGL((gemm_mfma<EPI_BF16>), dim3(D3 / 128, 1), dim3(256), 0, stream,
                       sn, in_wb, in_b, 64, D3, DD, snqkv, (float*)nullptr, FNULL);
    hipLaunchKernelGGL((gemm_mfma<EPI_BF16>), dim3(D3 / 128, 1), dim3(256), 0, stream,
                       ten, in_wb, in_b, 8, D3, DD, teqkv, (float*)nullptr, FNULL);
    hipLaunchKernelGGL(s_attn, dim3(HH, BB * TT), dim3(64), 0, stream, qkv, snqkv, teqkv, pmask, smix);
    hipLaunchKernelGGL(conv_mean, dim3(256), dim3(256), 0, stream, smix, conv_w, conv_b, smm);
    hipLaunchKernelGGL((gemm_mfma<EPI_RES>), dim3(DD / 128, 1), dim3(256), 0, stream,
                       smm, out_wb, out_b, 64, DD, DD, UNULL, outs, s);
    // 6. x MLP: outx += proj(gelu(fc(LN2(outx))))
    hipLaunchKernelGGL(ln_rows, dim3(NTOK), dim3(256), 0, stream, outx, FNULL, ln2_g, ln2_b, xn, NTOK);
    hipLaunchKernelGGL((gemm_mfma<EPI_GELU>), dim3(DFF / 128, (NTOK + 127) / 128), dim3(256), 0, stream,
                       xn, fc_wb, fc_b, NTOK, DFF, DD, hidden, (float*)nullptr, FNULL);
    hipLaunchKernelGGL((gemm_mfma<EPI_RES>), dim3(DD / 128, (NTOK + 127) / 128), dim3(256), 0, stream,
                       hidden, proj_wb, proj_b, NTOK, DD, DFF, UNULL, outx, outx);
    // 7. s MLP
    hipLaunchKernelGGL(ln_rows, dim3(64), dim3(256), 0, stream, outs, FNULL, ln2_g, ln2_b, ln2s, 64);
    hipLaunchKernelGGL((gemm_mfma<EPI_GELU>), dim3(DFF / 128, 1), dim3(256), 0, stream,
                       ln2s, fc_wb, fc_b, 64, DFF, DD, hids, (float*)nullptr, FNULL);
    hipLaunchKernelGGL((gemm_mfma<EPI_RES>), dim3(DD / 128, 1), dim3(256), 0, stream,
                       hids, proj_wb, proj_b, 64, DD, DFF, UNULL, outs, outs);
}

// Round 3
// 1888.185 us; speedup vs baseline: 5.8750x; 2.0350x over previous
//
#include <hip/hip_runtime.h>
#include <hip/hip_bf16.h>

// ---------------- problem constants ----------------
#define BB 8
#define TT 8
#define LL 257
#define DD 1024
#define HH 16
#define CC 64
#define SS 8
#define NTOK (BB*TT*LL)   // 16448
#define D3 (3*DD)         // 3072
#define DFF (4*DD)        // 4096

typedef unsigned short u16;   // bf16 bits
typedef __attribute__((ext_vector_type(8))) short short8;
typedef __attribute__((ext_vector_type(4))) float f32x4;

__device__ __forceinline__ float us2f(u16 u) {
    return __uint_as_float(((unsigned int)u) << 16);
}
__device__ __forceinline__ u16 f2us(float f) {
    unsigned int u = __float_as_uint(f);
    unsigned int rb = ((u >> 16) & 1u) + 0x7fffu;   // round-to-nearest-even
    return (u16)((u + rb) >> 16);
}

__device__ __forceinline__ void gload_lds16(const u16* g, u16* l) {
    __builtin_amdgcn_global_load_lds(
        (__attribute__((address_space(1))) void*)(void*)g,
        (__attribute__((address_space(3))) void*)(void*)l, 16, 0, 0);
}

// ---------------- fp32 -> bf16 weight conversion ----------------
__global__ __launch_bounds__(256)
void cvt_w(const float* __restrict__ in, u16* __restrict__ out, int n4)
{
    int i = blockIdx.x * 256 + threadIdx.x;
    if (i >= n4) return;
    float4 v = reinterpret_cast<const float4*>(in)[i];
    ushort4 o;
    o.x = f2us(v.x); o.y = f2us(v.y); o.z = f2us(v.z); o.w = f2us(v.w);
    reinterpret_cast<ushort4*>(out)[i] = o;
}

// ---------------- LayerNorm over last dim (1024), optional residual add ----------------
__global__ __launch_bounds__(256)
void ln_rows(const float* __restrict__ X, const float* __restrict__ R,
             const float* __restrict__ g, const float* __restrict__ bta,
             u16* __restrict__ out, int M)
{
    int row = blockIdx.x;
    if (row >= M) return;
    const float* x = X + (size_t)row * DD;
    const float* r = R ? R + (size_t)row * DD : nullptr;
    int t = threadIdx.x;
    float v[4]; float s1 = 0.f, s2 = 0.f;
#pragma unroll
    for (int i = 0; i < 4; ++i) {
        float val = x[t + 256 * i];
        if (r) val += r[t + 256 * i];
        v[i] = val; s1 += val; s2 += val * val;
    }
#pragma unroll
    for (int o = 32; o > 0; o >>= 1) { s1 += __shfl_xor(s1, o, 64); s2 += __shfl_xor(s2, o, 64); }
    __shared__ float red[10];
    int wid = t >> 6, lane = t & 63;
    if (lane == 0) { red[wid] = s1; red[4 + wid] = s2; }
    __syncthreads();
    if (t == 0) {
        float a = red[0] + red[1] + red[2] + red[3];
        float q = red[4] + red[5] + red[6] + red[7];
        float mu = a * (1.f / DD);
        float var = q * (1.f / DD) - mu * mu;
        red[8] = mu; red[9] = rsqrtf(var + 1e-5f);
    }
    __syncthreads();
    float mu = red[8], rs = red[9];
#pragma unroll
    for (int i = 0; i < 4; ++i) {
        int c = t + 256 * i;
        out[(size_t)row * DD + c] = f2us((v[i] - mu) * rs * g[c] + bta[c]);
    }
}

// ---------------- LayerNorm over whole (T,D) tensor (te) ----------------
__global__ __launch_bounds__(256)
void ln_te(const float* __restrict__ te, const float* __restrict__ g,
           const float* __restrict__ bta, u16* __restrict__ out)
{
    const int NE = TT * DD;   // 8192
    int t = threadIdx.x;
    float s1 = 0.f, s2 = 0.f;
    for (int i = t; i < NE; i += 256) { float v = te[i]; s1 += v; s2 += v * v; }
#pragma unroll
    for (int o = 32; o > 0; o >>= 1) { s1 += __shfl_xor(s1, o, 64); s2 += __shfl_xor(s2, o, 64); }
    __shared__ float red[10];
    int wid = t >> 6, lane = t & 63;
    if (lane == 0) { red[wid] = s1; red[4 + wid] = s2; }
    __syncthreads();
    if (t == 0) {
        float a = red[0] + red[1] + red[2] + red[3];
        float q = red[4] + red[5] + red[6] + red[7];
        float mu = a / (float)NE;
        float var = q / (float)NE - mu * mu;
        red[8] = mu; red[9] = rsqrtf(var + 1e-5f);
    }
    __syncthreads();
    float mu = red[8], rs = red[9];
    for (int i = t; i < NE; i += 256)
        out[i] = f2us((te[i] - mu) * rs * g[i] + bta[i]);
}

// ---------------- MFMA GEMM: C[m,j] = sum_k A[m,k]*W[j,k] (+bias) ----------------
enum { EPI_BF16 = 0, EPI_GELU = 1, EPI_RES = 2, EPI_F32 = 3 };

template<int EPI>
__global__ __launch_bounds__(256)
void gemm_mfma(const u16* __restrict__ A, const u16* __restrict__ W,
               const float* __restrict__ bias, int M, int N, int K,
               u16* __restrict__ outB, float* __restrict__ outF,
               const float* __restrict__ res)
{
    __shared__ u16 Als[128 * 32];
    __shared__ u16 Bls[128 * 32];
    const int tid = threadIdx.x;
    const int lane = tid & 63;
    const int wid = tid >> 6;
    const int wm = (wid >> 1) * 64, wn = (wid & 1) * 64;
    const int m0 = blockIdx.y * 128, n0 = blockIdx.x * 128;

    int o0 = tid, o1 = tid + 256;
    int g0 = o0 >> 6, kb0 = (o0 >> 4) & 3, r0 = o0 & 15;
    int g1 = o1 >> 6, kb1 = (o1 >> 4) & 3, r1 = o1 & 15;
    int ar0 = m0 + g0 * 16 + r0; if (ar0 >= M) ar0 = M - 1;
    int ar1 = m0 + g1 * 16 + r1; if (ar1 >= M) ar1 = M - 1;
    int br0 = n0 + g0 * 16 + r0;
    int br1 = n0 + g1 * 16 + r1;
    const u16* a0 = A + (size_t)ar0 * K + kb0 * 8;
    const u16* a1 = A + (size_t)ar1 * K + kb1 * 8;
    const u16* b0 = W + (size_t)br0 * K + kb0 * 8;
    const u16* b1 = W + (size_t)br1 * K + kb1 * 8;

    f32x4 acc[4][4];
#pragma unroll
    for (int i = 0; i < 4; ++i)
#pragma unroll
        for (int j = 0; j < 4; ++j)
            acc[i][j] = (f32x4){0.f, 0.f, 0.f, 0.f};

    for (int k0 = 0; k0 < K; k0 += 32) {
        gload_lds16(a0 + k0, &Als[o0 * 8]);
        gload_lds16(a1 + k0, &Als[o1 * 8]);
        gload_lds16(b0 + k0, &Bls[o0 * 8]);
        gload_lds16(b1 + k0, &Bls[o1 * 8]);
        __syncthreads();
        short8 af[4], bfr[4];
#pragma unroll
        for (int i = 0; i < 4; ++i)
            af[i] = *reinterpret_cast<const short8*>(&Als[((wm >> 4) + i) * 512 + lane * 8]);
#pragma unroll
        for (int j = 0; j < 4; ++j)
            bfr[j] = *reinterpret_cast<const short8*>(&Bls[((wn >> 4) + j) * 512 + lane * 8]);
#pragma unroll
        for (int i = 0; i < 4; ++i)
#pragma unroll
            for (int j = 0; j < 4; ++j)
                acc[i][j] = __builtin_amdgcn_mfma_f32_16x16x32_bf16(af[i], bfr[j], acc[i][j], 0, 0, 0);
        __syncthreads();
    }

    const int cn = lane & 15, cr = (lane >> 4) * 4;
#pragma unroll
    for (int i = 0; i < 4; ++i) {
#pragma unroll
        for (int r = 0; r < 4; ++r) {
            int m = m0 + wm + i * 16 + cr + r;
            if (m >= M) continue;
#pragma unroll
            for (int j = 0; j < 4; ++j) {
                int n = n0 + wn + j * 16 + cn;
                float c = acc[i][j][r];
                if (bias) c += bias[n];
                size_t o = (size_t)m * N + n;
                if (EPI == EPI_BF16) outB[o] = f2us(c);
                else if (EPI == EPI_GELU) { float gg = c / (1.f + __expf(-1.702f * c)); outB[o] = f2us(gg); }
                else if (EPI == EPI_RES) outF[o] = res[o] + c;
                else outF[o] = c;
            }
        }
    }
}

// ---------------- MFMA spatial attention: one block (4 waves) per (h, b*t) ----------------
// K in LDS row-major (stride 72 u16, 16B-aligned rows, ~2-way banks).
// V in LDS transposed Vt[c][k] (stride 296 u16), keys padded/zeroed to 288.
// Per wave: 16-row Q-tile -> 17 score tiles (padded keys masked) -> in-register
// softmax (16-lane shfl reduce) -> P streamed via small per-wave LDS chunk -> PV.
#define KSTR 72
#define VSTR 296
#define PSTR 40

__global__ __launch_bounds__(256)
void spatial_attn(const u16* __restrict__ qkv, u16* __restrict__ mix)
{
    const int h = blockIdx.x, bt = blockIdx.y;
    const int hoff = h * CC;
    const size_t base = (size_t)bt * LL * D3;
    __shared__ u16 Kls[257 * KSTR];
    __shared__ u16 Vt[64 * VSTR];
    __shared__ u16 Pb[4][16 * PSTR];
    const int tid = threadIdx.x, lane = tid & 63, w = tid >> 6;
    const int c15 = lane & 15, g = lane >> 4;

    // stage K rows (16B per thread-slot, coalesced within rows)
    for (int idx = tid; idx < 257 * 8; idx += 256) {
        int row = idx >> 3, c8 = (idx & 7) << 3;
        float4 v = *reinterpret_cast<const float4*>(&qkv[base + (size_t)row * D3 + DD + hoff + c8]);
        *reinterpret_cast<float4*>(&Kls[row * KSTR + c8]) = v;
    }
    // stage V transposed; zero-fill padded keys 257..287 (0*NaN hazard)
    for (int idx = tid; idx < 288 * 64; idx += 256) {
        int key = idx >> 6, c = idx & 63;
        u16 v = 0;
        if (key < 257) v = qkv[base + (size_t)key * D3 + 2 * DD + hoff + c];
        Vt[c * VSTR + key] = v;
    }
    __syncthreads();

    u16* pb = Pb[w];
    for (int qt = w; qt < 17; qt += 4) {
        int qrow = qt * 16 + c15; if (qrow > 256) qrow = 256;
        const u16* qp = &qkv[base + (size_t)qrow * D3 + hoff + g * 8];
        short8 a0 = *reinterpret_cast<const short8*>(qp);
        short8 a1 = *reinterpret_cast<const short8*>(qp + 32);

        f32x4 sc[17];
#pragma unroll
        for (int t = 0; t < 17; ++t) sc[t] = (f32x4){0.f, 0.f, 0.f, 0.f};
#pragma unroll
        for (int t = 0; t < 17; ++t) {
            int krow = t * 16 + c15; if (krow > 256) krow = 256;
            short8 b0 = *reinterpret_cast<const short8*>(&Kls[krow * KSTR + g * 8]);
            short8 b1 = *reinterpret_cast<const short8*>(&Kls[krow * KSTR + 32 + g * 8]);
            sc[t] = __builtin_amdgcn_mfma_f32_16x16x32_bf16(a0, b0, sc[t], 0, 0, 0);
            sc[t] = __builtin_amdgcn_mfma_f32_16x16x32_bf16(a1, b1, sc[t], 0, 0, 0);
        }

        // softmax: row q = qt*16 + 4g + r ; this lane holds k = 16t + c15
        const bool lastv = (c15 == 0);   // tile 16: only k=256 valid
#pragma unroll
        for (int r = 0; r < 4; ++r) {
            float mx = -1e30f;
#pragma unroll
            for (int t = 0; t < 17; ++t) {
                float v = sc[t][r] * 0.125f;
                if (t == 16 && !lastv) v = -1e30f;
                sc[t][r] = v;
                mx = fmaxf(mx, v);
            }
            mx = fmaxf(mx, __shfl_xor(mx, 1, 64));
            mx = fmaxf(mx, __shfl_xor(mx, 2, 64));
            mx = fmaxf(mx, __shfl_xor(mx, 4, 64));
            mx = fmaxf(mx, __shfl_xor(mx, 8, 64));
            float sum = 0.f;
#pragma unroll
            for (int t = 0; t < 17; ++t) { float e = __expf(sc[t][r] - mx); sc[t][r] = e; sum += e; }
            sum += __shfl_xor(sum, 1, 64);
            sum += __shfl_xor(sum, 2, 64);
            sum += __shfl_xor(sum, 4, 64);
            sum += __shfl_xor(sum, 8, 64);
            float is = 1.f / sum;
#pragma unroll
            for (int t = 0; t < 17; ++t) sc[t][r] *= is;
        }

        // PV: 9 chunks of 32 keys; P goes through per-wave LDS chunk buffer
        f32x4 oacc[4];
#pragma unroll
        for (int ct = 0; ct < 4; ++ct) oacc[ct] = (f32x4){0.f, 0.f, 0.f, 0.f};
#pragma unroll
        for (int k0 = 0; k0 < 9; ++k0) {
            const int t0 = 2 * k0, t1 = 2 * k0 + 1;
#pragma unroll
            for (int r = 0; r < 4; ++r) {
                pb[(4 * g + r) * PSTR + c15]      = f2us(sc[t0][r]);
                pb[(4 * g + r) * PSTR + 16 + c15] = (t1 < 17) ? f2us(sc[t1][r]) : (u16)0;
            }
            short8 pa = *reinterpret_cast<const short8*>(&pb[c15 * PSTR + 8 * g]);
#pragma unroll
            for (int ct = 0; ct < 4; ++ct) {
                short8 vb = *reinterpret_cast<const short8*>(&Vt[(16 * ct + c15) * VSTR + 32 * k0 + 8 * g]);
                oacc[ct] = __builtin_amdgcn_mfma_f32_16x16x32_bf16(pa, vb, oacc[ct], 0, 0, 0);
            }
        }

        // epilogue: O[q][c], q = qt*16 + 4g + r, c = 16ct + c15
#pragma unroll
        for (int r = 0; r < 4; ++r) {
            int q = qt * 16 + 4 * g + r;
            if (q >= LL) continue;
            size_t ob = ((size_t)bt * LL + q) * DD + hoff;
#pragma unroll
            for (int ct = 0; ct < 4; ++ct)
                mix[ob + 16 * ct + c15] = f2us(oacc[ct][r]);
        }
    }
}

// ---------------- syno-token attention: one block (1 wave) per (h, b*t) ----------------
__global__ __launch_bounds__(64)
void s_attn(const u16* __restrict__ qkv, const u16* __restrict__ snqkv,
            const u16* __restrict__ teqkv, const float* __restrict__ pmask,
            float* __restrict__ smix)
{
    const int h = blockIdx.x, bt = blockIdx.y, b = bt >> 3, t = bt & 7;
    const int hoff = h * CC, lane = threadIdx.x;
    __shared__ u16 Kls[256 * 66];
    __shared__ float pls[256];
    const size_t base = (size_t)bt * LL * D3;
    const float tek = us2f(teqkv[t * D3 + DD + hoff + lane]);
    const float tev = us2f(teqkv[t * D3 + 2 * DD + hoff + lane]);
    for (int key = 0; key < 256; ++key) {
        float kv = us2f(qkv[base + (size_t)(key + 1) * D3 + DD + hoff + lane]) + tek;
        Kls[key * 66 + lane] = f2us(kv);
    }
    const float* pm = pmask + (size_t)bt * 256;
    const u16* vgl = qkv + base + 2 * DD + hoff + lane;
    for (int q = 0; q < SS; ++q) {
        float qc = us2f(snqkv[((size_t)(b * SS + q)) * D3 + hoff + lane]) * 0.125f;
        float sc[4] = {0.f, 0.f, 0.f, 0.f};
        for (int c = 0; c < CC; ++c) {
            float qv = __shfl(qc, c, 64);
#pragma unroll
            for (int j = 0; j < 4; ++j)
                sc[j] += qv * us2f(Kls[(lane + 64 * j) * 66 + c]);
        }
#pragma unroll
        for (int j = 0; j < 4; ++j) sc[j] += pm[lane + 64 * j];
        float mx = fmaxf(fmaxf(sc[0], sc[1]), fmaxf(sc[2], sc[3]));
#pragma unroll
        for (int o = 32; o > 0; o >>= 1) mx = fmaxf(mx, __shfl_xor(mx, o, 64));
        float sum = 0.f;
#pragma unroll
        for (int j = 0; j < 4; ++j) { sc[j] = __expf(sc[j] - mx); sum += sc[j]; }
#pragma unroll
        for (int o = 32; o > 0; o >>= 1) sum += __shfl_xor(sum, o, 64);
        float inv = 1.f / sum;
#pragma unroll
        for (int j = 0; j < 4; ++j) pls[lane + 64 * j] = sc[j] * inv;
        float acc = 0.f;
        for (int key = 0; key < 256; ++key)
            acc += pls[key] * (us2f(vgl[(size_t)(key + 1) * D3]) + tev);
        smix[(((size_t)bt * SS + q) * HH + h) * CC + lane] = acc;
    }
}

// ---------------- depthwise temporal conv + residual + mean over T ----------------
__global__ __launch_bounds__(256)
void conv_mean(const float* __restrict__ smix, const float* __restrict__ cw,
               const float* __restrict__ cb, u16* __restrict__ out)
{
    int idx = blockIdx.x * 256 + threadIdx.x;
    int d = idx & 1023;
    int bs = idx >> 10;
    int b = bs >> 3, s_ = bs & 7;
    float z[TT];
#pragma unroll
    for (int t = 0; t < TT; ++t)
        z[t] = smix[((size_t)(b * TT + t) * SS + s_) * DD + d];
    float w0 = cw[d * 3], w1 = cw[d * 3 + 1], w2 = cw[d * 3 + 2];
    float acc = 0.f;
#pragma unroll
    for (int t = 0; t < TT; ++t) {
        float zc = w1 * z[t];
        if (t > 0)      zc += w0 * z[t - 1];
        if (t < TT - 1) zc += w2 * z[t + 1];
        acc += z[t] + zc;
    }
    out[(size_t)bs * DD + d] = f2us(acc * 0.125f + cb[d]);
}

// ---------------- host: launch sequence ----------------
extern "C" void kernel_launch(void* const* d_in, const int* in_sizes, int n_in,
                              void* d_out, int out_size, void* d_ws, size_t ws_size,
                              hipStream_t stream)
{
    const float* x      = (const float*)d_in[0];
    const float* s      = (const float*)d_in[1];
    const float* te     = (const float*)d_in[2];
    const float* pmask  = (const float*)d_in[3];
    const float* in_w   = (const float*)d_in[4];
    const float* in_b   = (const float*)d_in[5];
    const float* out_w  = (const float*)d_in[6];
    const float* out_b  = (const float*)d_in[7];
    const float* ln1_g  = (const float*)d_in[8];
    const float* ln1_b  = (const float*)d_in[9];
    const float* ln2_g  = (const float*)d_in[10];
    const float* ln2_b  = (const float*)d_in[11];
    const float* fc_w   = (const float*)d_in[12];
    const float* fc_b   = (const float*)d_in[13];
    const float* proj_w = (const float*)d_in[14];
    const float* proj_b = (const float*)d_in[15];
    const float* smlp_g = (const float*)d_in[16];
    const float* smlp_b = (const float*)d_in[17];
    const float* w1     = (const float*)d_in[18];
    const float* w2     = (const float*)d_in[19];
    const float* lnte_g = (const float*)d_in[20];
    const float* lnte_b = (const float*)d_in[21];
    const float* conv_w = (const float*)d_in[22];
    const float* conv_b = (const float*)d_in[23];

    float* outx = (float*)d_out;                     // [NTOK, 1024]
    float* outs = outx + (size_t)NTOK * DD;          // [64, 1024]

    char* ws = (char*)d_ws;
    u16* qkv    = (u16*)ws;                                      // [NTOK,3072] bf16
    u16* mixb   = (u16*)(ws + (size_t)NTOK * D3 * 2);            // [NTOK,1024] bf16
    u16* hidden = qkv;                                           // [NTOK,4096] overlay (exact)
    u16* xn     = (u16*)(ws + (size_t)NTOK * DFF * 2);           // [NTOK,1024] bf16
    char* sm    = ws + (size_t)NTOK * DFF * 2 + (size_t)NTOK * DD * 2;
    u16*  s_ln0 = (u16*)sm;   sm += 64 * DD * 2;
    u16*  h1    = (u16*)sm;   sm += 64 * 128 * 2;
    float* smlp = (float*)sm; sm += 64 * DD * 4;
    u16*  sn    = (u16*)sm;   sm += 64 * DD * 2;
    u16*  snqkv = (u16*)sm;   sm += 64 * D3 * 2;
    u16*  ten   = (u16*)sm;   sm += 8 * DD * 2;
    u16*  teqkv = (u16*)sm;   sm += 8 * D3 * 2;
    float* smix = (float*)sm; sm += (size_t)BB * TT * SS * DD * 4;
    u16*  smm   = (u16*)sm;   sm += 64 * DD * 2;
    u16*  ln2s  = (u16*)sm;   sm += 64 * DD * 2;
    u16*  hids  = (u16*)sm;   sm += 64 * DFF * 2;
    // bf16 weights
    u16* in_wb   = (u16*)sm;  sm += (size_t)D3 * DD * 2;
    u16* out_wb  = (u16*)sm;  sm += (size_t)DD * DD * 2;
    u16* fc_wb   = (u16*)sm;  sm += (size_t)DFF * DD * 2;
    u16* proj_wb = (u16*)sm;  sm += (size_t)DD * DFF * 2;
    u16* w1b     = (u16*)sm;  sm += (size_t)128 * DD * 2;
    u16* w2b     = (u16*)sm;  sm += (size_t)DD * 128 * 2;

    const float* FNULL = nullptr;
    u16* UNULL = nullptr;

    // 0. weight conversions
    auto cvt = [&](const float* src, u16* dst, int n) {
        hipLaunchKernelGGL(cvt_w, dim3((n / 4 + 255) / 256), dim3(256), 0, stream, src, dst, n / 4);
    };
    cvt(in_w,   in_wb,   D3 * DD);
    cvt(out_w,  out_wb,  DD * DD);
    cvt(fc_w,   fc_wb,   DFF * DD);
    cvt(proj_w, proj_wb, DD * DFF);
    cvt(w1,     w1b,     128 * DD);
    cvt(w2,     w2b,     DD * 128);

    // 1. xn = LN1(x)
    hipLaunchKernelGGL(ln_rows, dim3(NTOK), dim3(256), 0, stream, x, FNULL, ln1_g, ln1_b, xn, NTOK);
    // 2. qkv = xn @ in_proj_w^T + b
    hipLaunchKernelGGL((gemm_mfma<EPI_BF16>), dim3(D3 / 128, (NTOK + 127) / 128), dim3(256), 0, stream,
                       xn, in_wb, in_b, NTOK, D3, DD, qkv, (float*)nullptr, FNULL);
    // 3. spatial attention -> mix (MFMA flash)
    hipLaunchKernelGGL(spatial_attn, dim3(HH, BB * TT), dim3(256), 0, stream, qkv, mixb);
    // 4. outx = x + mix @ out_w^T + out_b
    hipLaunchKernelGGL((gemm_mfma<EPI_RES>), dim3(DD / 128, (NTOK + 127) / 128), dim3(256), 0, stream,
                       mixb, out_wb, out_b, NTOK, DD, DD, UNULL, outx, x);
    // 5. syno-token branch
    hipLaunchKernelGGL(ln_rows, dim3(64), dim3(256), 0, stream, s, FNULL, smlp_g, smlp_b, s_ln0, 64);
    hipLaunchKernelGGL((gemm_mfma<EPI_BF16>), dim3(1, 1), dim3(256), 0, stream,
                       s_ln0, w1b, FNULL, 64, 128, DD, h1, (float*)nullptr, FNULL);
    hipLaunchKernelGGL((gemm_mfma<EPI_F32>), dim3(DD / 128, 1), dim3(256), 0, stream,
                       h1, w2b, FNULL, 64, DD, 128, UNULL, smlp, FNULL);
    hipLaunchKernelGGL(ln_rows, dim3(64), dim3(256), 0, stream, s, smlp, ln1_g, ln1_b, sn, 64);
    hipLaunchKernelGGL(ln_te, dim3(1), dim3(256), 0, stream, te, lnte_g, lnte_b, ten);
    hipLaunchKernelGGL((gemm_mfma<EPI_BF16>), dim3(D3 / 128, 1), dim3(256), 0, stream,
                       sn, in_wb, in_b, 64, D3, DD, snqkv, (float*)nullptr, FNULL);
    hipLaunchKernelGGL((gemm_mfma<EPI_BF16>), dim3(D3 / 128, 1), dim3(256), 0, stream,
                       ten, in_wb, in_b, 8, D3, DD, teqkv, (float*)nullptr, FNULL);
    hipLaunchKernelGGL(s_attn, dim3(HH, BB * TT), dim3(64), 0, stream, qkv, snqkv, teqkv, pmask, smix);
    hipLaunchKernelGGL(conv_mean, dim3(256), dim3(256), 0, stream, smix, conv_w, conv_b, smm);
    hipLaunchKernelGGL((gemm_mfma<EPI_RES>), dim3(DD / 128, 1), dim3(256), 0, stream,
                       smm, out_wb, out_b, 64, DD, DD, UNULL, outs, s);
    // 6. x MLP: outx += proj(gelu(fc(LN2(outx))))
    hipLaunchKernelGGL(ln_rows, dim3(NTOK), dim3(256), 0, stream, outx, FNULL, ln2_g, ln2_b, xn, NTOK);
    hipLaunchKernelGGL((gemm_mfma<EPI_GELU>), dim3(DFF / 128, (NTOK + 127) / 128), dim3(256), 0, stream,
                       xn, fc_wb, fc_b, NTOK, DFF, DD, hidden, (float*)nullptr, FNULL);
    hipLaunchKernelGGL((gemm_mfma<EPI_RES>), dim3(DD / 128, (NTOK + 127) / 128), dim3(256), 0, stream,
                       hidden, proj_wb, proj_b, NTOK, DD, DFF, UNULL, outx, outx);
    // 7. s MLP
    hipLaunchKernelGGL(ln_rows, dim3(64), dim3(256), 0, stream, outs, FNULL, ln2_g, ln2_b, ln2s, 64);
    hipLaunchKernelGGL((gemm_mfma<EPI_GELU>), dim3(DFF / 128, 1), dim3(256), 0, stream,
                       ln2s, fc_wb, fc_b, 64, DFF, DD, hids, (float*)nullptr, FNULL);
    hipLaunchKernelGGL((gemm_mfma<EPI_RES>), dim3(DD / 128, 1), dim3(256), 0, stream,
                       hids, proj_wb, proj_b, 64, DD, DFF, UNULL, outs, outs);
}

// Round 4
// 1734.994 us; speedup vs baseline: 6.3938x; 1.0883x over previous
//
#include <hip/hip_runtime.h>
#include <hip/hip_bf16.h>

// ---------------- problem constants ----------------
#define BB 8
#define TT 8
#define LL 257
#define DD 1024
#define HH 16
#define CC 64
#define SS 8
#define NTOK (BB*TT*LL)   // 16448
#define D3 (3*DD)         // 3072
#define DFF (4*DD)        // 4096

typedef unsigned short u16;   // bf16 bits
typedef __attribute__((ext_vector_type(8))) short short8;
typedef __attribute__((ext_vector_type(4))) short short4v;
typedef __attribute__((ext_vector_type(4))) float f32x4;

__device__ __forceinline__ float us2f(u16 u) {
    return __uint_as_float(((unsigned int)u) << 16);
}
__device__ __forceinline__ u16 f2us(float f) {
    unsigned int u = __float_as_uint(f);
    unsigned int rb = ((u >> 16) & 1u) + 0x7fffu;   // round-to-nearest-even
    return (u16)((u + rb) >> 16);
}

__device__ __forceinline__ void gload_lds16(const u16* g, u16* l) {
    __builtin_amdgcn_global_load_lds(
        (__attribute__((address_space(1))) void*)(void*)g,
        (__attribute__((address_space(3))) void*)(void*)l, 16, 0, 0);
}

// ---------------- fp32 -> bf16 weight conversion ----------------
__global__ __launch_bounds__(256)
void cvt_w(const float* __restrict__ in, u16* __restrict__ out, int n4)
{
    int i = blockIdx.x * 256 + threadIdx.x;
    if (i >= n4) return;
    float4 v = reinterpret_cast<const float4*>(in)[i];
    ushort4 o;
    o.x = f2us(v.x); o.y = f2us(v.y); o.z = f2us(v.z); o.w = f2us(v.w);
    reinterpret_cast<ushort4*>(out)[i] = o;
}

// ---------------- LayerNorm over last dim (1024), optional residual add ----------------
__global__ __launch_bounds__(256)
void ln_rows(const float* __restrict__ X, const float* __restrict__ R,
             const float* __restrict__ g, const float* __restrict__ bta,
             u16* __restrict__ out, int M)
{
    int row = blockIdx.x;
    if (row >= M) return;
    const float* x = X + (size_t)row * DD;
    const float* r = R ? R + (size_t)row * DD : nullptr;
    int t = threadIdx.x;
    float v[4]; float s1 = 0.f, s2 = 0.f;
#pragma unroll
    for (int i = 0; i < 4; ++i) {
        float val = x[t + 256 * i];
        if (r) val += r[t + 256 * i];
        v[i] = val; s1 += val; s2 += val * val;
    }
#pragma unroll
    for (int o = 32; o > 0; o >>= 1) { s1 += __shfl_xor(s1, o, 64); s2 += __shfl_xor(s2, o, 64); }
    __shared__ float red[10];
    int wid = t >> 6, lane = t & 63;
    if (lane == 0) { red[wid] = s1; red[4 + wid] = s2; }
    __syncthreads();
    if (t == 0) {
        float a = red[0] + red[1] + red[2] + red[3];
        float q = red[4] + red[5] + red[6] + red[7];
        float mu = a * (1.f / DD);
        float var = q * (1.f / DD) - mu * mu;
        red[8] = mu; red[9] = rsqrtf(var + 1e-5f);
    }
    __syncthreads();
    float mu = red[8], rs = red[9];
#pragma unroll
    for (int i = 0; i < 4; ++i) {
        int c = t + 256 * i;
        out[(size_t)row * DD + c] = f2us((v[i] - mu) * rs * g[c] + bta[c]);
    }
}

// ---------------- LayerNorm over whole (T,D) tensor (te) ----------------
__global__ __launch_bounds__(256)
void ln_te(const float* __restrict__ te, const float* __restrict__ g,
           const float* __restrict__ bta, u16* __restrict__ out)
{
    const int NE = TT * DD;   // 8192
    int t = threadIdx.x;
    float s1 = 0.f, s2 = 0.f;
    for (int i = t; i < NE; i += 256) { float v = te[i]; s1 += v; s2 += v * v; }
#pragma unroll
    for (int o = 32; o > 0; o >>= 1) { s1 += __shfl_xor(s1, o, 64); s2 += __shfl_xor(s2, o, 64); }
    __shared__ float red[10];
    int wid = t >> 6, lane = t & 63;
    if (lane == 0) { red[wid] = s1; red[4 + wid] = s2; }
    __syncthreads();
    if (t == 0) {
        float a = red[0] + red[1] + red[2] + red[3];
        float q = red[4] + red[5] + red[6] + red[7];
        float mu = a / (float)NE;
        float var = q / (float)NE - mu * mu;
        red[8] = mu; red[9] = rsqrtf(var + 1e-5f);
    }
    __syncthreads();
    float mu = red[8], rs = red[9];
    for (int i = t; i < NE; i += 256)
        out[i] = f2us((te[i] - mu) * rs * g[i] + bta[i]);
}

// ---------------- MFMA GEMM: C[m,j] = sum_k A[m,k]*W[j,k] (+bias) ----------------
// T1: bijective XCD-chunked swizzle (m204) so blocks sharing an A panel
// co-reside on one XCD's L2 (A fetched ~once instead of 8x).
enum { EPI_BF16 = 0, EPI_GELU = 1, EPI_RES = 2, EPI_F32 = 3 };

template<int EPI>
__global__ __launch_bounds__(256)
void gemm_mfma(const u16* __restrict__ A, const u16* __restrict__ W,
               const float* __restrict__ bias, int M, int N, int K,
               u16* __restrict__ outB, float* __restrict__ outF,
               const float* __restrict__ res)
{
    __shared__ u16 Als[128 * 32];
    __shared__ u16 Bls[128 * 32];
    const int tid = threadIdx.x;
    const int lane = tid & 63;
    const int wid = tid >> 6;
    const int wm = (wid >> 1) * 64, wn = (wid & 1) * 64;

    // XCD-chunked bijective swizzle
    const int gx = gridDim.x;
    const int nwg = gx * gridDim.y;
    int bid = blockIdx.y * gx + blockIdx.x;
    int qq = nwg >> 3, rr = nwg & 7;
    int xcd = bid & 7, idx = bid >> 3;
    int nb = (xcd < rr ? xcd * (qq + 1) : rr * (qq + 1) + (xcd - rr) * qq) + idx;
    const int m0 = (nb / gx) * 128, n0 = (nb % gx) * 128;

    int o0 = tid, o1 = tid + 256;
    int g0 = o0 >> 6, kb0 = (o0 >> 4) & 3, r0 = o0 & 15;
    int g1 = o1 >> 6, kb1 = (o1 >> 4) & 3, r1 = o1 & 15;
    int ar0 = m0 + g0 * 16 + r0; if (ar0 >= M) ar0 = M - 1;
    int ar1 = m0 + g1 * 16 + r1; if (ar1 >= M) ar1 = M - 1;
    int br0 = n0 + g0 * 16 + r0;
    int br1 = n0 + g1 * 16 + r1;
    const u16* a0 = A + (size_t)ar0 * K + kb0 * 8;
    const u16* a1 = A + (size_t)ar1 * K + kb1 * 8;
    const u16* b0 = W + (size_t)br0 * K + kb0 * 8;
    const u16* b1 = W + (size_t)br1 * K + kb1 * 8;

    f32x4 acc[4][4];
#pragma unroll
    for (int i = 0; i < 4; ++i)
#pragma unroll
        for (int j = 0; j < 4; ++j)
            acc[i][j] = (f32x4){0.f, 0.f, 0.f, 0.f};

    for (int k0 = 0; k0 < K; k0 += 32) {
        gload_lds16(a0 + k0, &Als[o0 * 8]);
        gload_lds16(a1 + k0, &Als[o1 * 8]);
        gload_lds16(b0 + k0, &Bls[o0 * 8]);
        gload_lds16(b1 + k0, &Bls[o1 * 8]);
        __syncthreads();
        short8 af[4], bfr[4];
#pragma unroll
        for (int i = 0; i < 4; ++i)
            af[i] = *reinterpret_cast<const short8*>(&Als[((wm >> 4) + i) * 512 + lane * 8]);
#pragma unroll
        for (int j = 0; j < 4; ++j)
            bfr[j] = *reinterpret_cast<const short8*>(&Bls[((wn >> 4) + j) * 512 + lane * 8]);
        __builtin_amdgcn_s_setprio(1);
#pragma unroll
        for (int i = 0; i < 4; ++i)
#pragma unroll
            for (int j = 0; j < 4; ++j)
                acc[i][j] = __builtin_amdgcn_mfma_f32_16x16x32_bf16(af[i], bfr[j], acc[i][j], 0, 0, 0);
        __builtin_amdgcn_s_setprio(0);
        __syncthreads();
    }

    const int cn = lane & 15, cr = (lane >> 4) * 4;
#pragma unroll
    for (int i = 0; i < 4; ++i) {
#pragma unroll
        for (int r = 0; r < 4; ++r) {
            int m = m0 + wm + i * 16 + cr + r;
            if (m >= M) continue;
#pragma unroll
            for (int j = 0; j < 4; ++j) {
                int n = n0 + wn + j * 16 + cn;
                float c = acc[i][j][r];
                if (bias) c += bias[n];
                size_t o = (size_t)m * N + n;
                if (EPI == EPI_BF16) outB[o] = f2us(c);
                else if (EPI == EPI_GELU) { float gg = c / (1.f + __expf(-1.702f * c)); outB[o] = f2us(gg); }
                else if (EPI == EPI_RES) outF[o] = res[o] + c;
                else outF[o] = c;
            }
        }
    }
}

// ---------------- MFMA spatial attention: one block (4 waves) per (h, b*t) ----------------
#define KSTR 72
#define VSTR 296
#define PSTR 40

__global__ __launch_bounds__(256)
void spatial_attn(const u16* __restrict__ qkv, u16* __restrict__ mix)
{
    const int h = blockIdx.x, bt = blockIdx.y;
    const int hoff = h * CC;
    const size_t base = (size_t)bt * LL * D3;
    __shared__ u16 Kls[257 * KSTR];
    __shared__ u16 Vt[64 * VSTR];
    __shared__ u16 Pb[4][16 * PSTR];
    const int tid = threadIdx.x, lane = tid & 63, w = tid >> 6;
    const int c15 = lane & 15, g = lane >> 4;

    for (int idx = tid; idx < 257 * 8; idx += 256) {
        int row = idx >> 3, c8 = (idx & 7) << 3;
        float4 v = *reinterpret_cast<const float4*>(&qkv[base + (size_t)row * D3 + DD + hoff + c8]);
        *reinterpret_cast<float4*>(&Kls[row * KSTR + c8]) = v;
    }
    for (int idx = tid; idx < 288 * 64; idx += 256) {
        int key = idx >> 6, c = idx & 63;
        u16 v = 0;
        if (key < 257) v = qkv[base + (size_t)key * D3 + 2 * DD + hoff + c];
        Vt[c * VSTR + key] = v;
    }
    __syncthreads();

    u16* pb = Pb[w];
    for (int qt = w; qt < 17; qt += 4) {
        int qrow = qt * 16 + c15; if (qrow > 256) qrow = 256;
        const u16* qp = &qkv[base + (size_t)qrow * D3 + hoff + g * 8];
        short8 a0 = *reinterpret_cast<const short8*>(qp);
        short8 a1 = *reinterpret_cast<const short8*>(qp + 32);

        f32x4 sc[17];
#pragma unroll
        for (int t = 0; t < 17; ++t) sc[t] = (f32x4){0.f, 0.f, 0.f, 0.f};
        __builtin_amdgcn_s_setprio(1);
#pragma unroll
        for (int t = 0; t < 17; ++t) {
            int krow = t * 16 + c15; if (krow > 256) krow = 256;
            short8 b0 = *reinterpret_cast<const short8*>(&Kls[krow * KSTR + g * 8]);
            short8 b1 = *reinterpret_cast<const short8*>(&Kls[krow * KSTR + 32 + g * 8]);
            sc[t] = __builtin_amdgcn_mfma_f32_16x16x32_bf16(a0, b0, sc[t], 0, 0, 0);
            sc[t] = __builtin_amdgcn_mfma_f32_16x16x32_bf16(a1, b1, sc[t], 0, 0, 0);
        }
        __builtin_amdgcn_s_setprio(0);

        const bool lastv = (c15 == 0);
#pragma unroll
        for (int r = 0; r < 4; ++r) {
            float mx = -1e30f;
#pragma unroll
            for (int t = 0; t < 17; ++t) {
                float v = sc[t][r] * 0.125f;
                if (t == 16 && !lastv) v = -1e30f;
                sc[t][r] = v;
                mx = fmaxf(mx, v);
            }
            mx = fmaxf(mx, __shfl_xor(mx, 1, 64));
            mx = fmaxf(mx, __shfl_xor(mx, 2, 64));
            mx = fmaxf(mx, __shfl_xor(mx, 4, 64));
            mx = fmaxf(mx, __shfl_xor(mx, 8, 64));
            float sum = 0.f;
#pragma unroll
            for (int t = 0; t < 17; ++t) { float e = __expf(sc[t][r] - mx); sc[t][r] = e; sum += e; }
            sum += __shfl_xor(sum, 1, 64);
            sum += __shfl_xor(sum, 2, 64);
            sum += __shfl_xor(sum, 4, 64);
            sum += __shfl_xor(sum, 8, 64);
            float is = 1.f / sum;
#pragma unroll
            for (int t = 0; t < 17; ++t) sc[t][r] *= is;
        }

        f32x4 oacc[4];
#pragma unroll
        for (int ct = 0; ct < 4; ++ct) oacc[ct] = (f32x4){0.f, 0.f, 0.f, 0.f};
#pragma unroll
        for (int k0 = 0; k0 < 9; ++k0) {
            const int t0 = 2 * k0, t1 = 2 * k0 + 1;
#pragma unroll
            for (int r = 0; r < 4; ++r) {
                pb[(4 * g + r) * PSTR + c15]      = f2us(sc[t0][r]);
                pb[(4 * g + r) * PSTR + 16 + c15] = (t1 < 17) ? f2us(sc[t1][r]) : (u16)0;
            }
            short8 pa = *reinterpret_cast<const short8*>(&pb[c15 * PSTR + 8 * g]);
            __builtin_amdgcn_s_setprio(1);
#pragma unroll
            for (int ct = 0; ct < 4; ++ct) {
                short8 vb = *reinterpret_cast<const short8*>(&Vt[(16 * ct + c15) * VSTR + 32 * k0 + 8 * g]);
                oacc[ct] = __builtin_amdgcn_mfma_f32_16x16x32_bf16(pa, vb, oacc[ct], 0, 0, 0);
            }
            __builtin_amdgcn_s_setprio(0);
        }

#pragma unroll
        for (int r = 0; r < 4; ++r) {
            int q = qt * 16 + 4 * g + r;
            if (q >= LL) continue;
            size_t ob = ((size_t)bt * LL + q) * DD + hoff;
#pragma unroll
            for (int ct = 0; ct < 4; ++ct)
                mix[ob + 16 * ct + c15] = f2us(oacc[ct][r]);
        }
    }
}

// ---------------- syno-token attention: one block (4 waves) per (h, b*t) ----------------
// K(+te_k) and V(+te_v) staged in LDS (stride 68 u16 = 34 dwords -> 2-way banks);
// 4 waves x 2 queries each; softmax/PV per wave.
#define SK 68

__global__ __launch_bounds__(256)
void s_attn(const u16* __restrict__ qkv, const u16* __restrict__ snqkv,
            const u16* __restrict__ teqkv, const float* __restrict__ pmask,
            float* __restrict__ smix)
{
    const int h = blockIdx.x, bt = blockIdx.y, b = bt >> 3, t = bt & 7;
    const int hoff = h * CC;
    const int tid = threadIdx.x, lane = tid & 63, w = tid >> 6;
    __shared__ u16 Kls[256 * SK];
    __shared__ u16 Vls[256 * SK];
    __shared__ float pls[4][256];
    const size_t base = (size_t)bt * LL * D3;

    // staging: thread handles 8 channels (c8..c8+7) of key rows (tid>>3)+32*pass
    const int c8 = (tid & 7) * 8;
    const u16* tekp = &teqkv[t * D3 + DD + hoff + c8];
    const u16* tevp = &teqkv[t * D3 + 2 * DD + hoff + c8];
    float tek[8], tev[8];
#pragma unroll
    for (int j = 0; j < 8; ++j) { tek[j] = us2f(tekp[j]); tev[j] = us2f(tevp[j]); }
#pragma unroll
    for (int pass = 0; pass < 8; ++pass) {
        int key = (tid >> 3) + 32 * pass;
        const u16* kp = &qkv[base + (size_t)(key + 1) * D3 + DD + hoff + c8];
        const u16* vp = &qkv[base + (size_t)(key + 1) * D3 + 2 * DD + hoff + c8];
        short4v k0 = *reinterpret_cast<const short4v*>(kp);
        short4v k1 = *reinterpret_cast<const short4v*>(kp + 4);
        short4v v0 = *reinterpret_cast<const short4v*>(vp);
        short4v v1 = *reinterpret_cast<const short4v*>(vp + 4);
        short4v ok0, ok1, ov0, ov1;
#pragma unroll
        for (int j = 0; j < 4; ++j) {
            ok0[j] = (short)f2us(us2f((u16)k0[j]) + tek[j]);
            ok1[j] = (short)f2us(us2f((u16)k1[j]) + tek[4 + j]);
            ov0[j] = (short)f2us(us2f((u16)v0[j]) + tev[j]);
            ov1[j] = (short)f2us(us2f((u16)v1[j]) + tev[4 + j]);
        }
        *reinterpret_cast<short4v*>(&Kls[key * SK + c8]) = ok0;
        *reinterpret_cast<short4v*>(&Kls[key * SK + c8 + 4]) = ok1;
        *reinterpret_cast<short4v*>(&Vls[key * SK + c8]) = ov0;
        *reinterpret_cast<short4v*>(&Vls[key * SK + c8 + 4]) = ov1;
    }
    __syncthreads();

    const float* pm = pmask + (size_t)bt * 256;
    for (int qi = w; qi < SS; qi += 4) {
        float qc = us2f(snqkv[(size_t)(b * SS + qi) * D3 + hoff + lane]) * 0.125f;
        float sc[4] = {0.f, 0.f, 0.f, 0.f};
        for (int c = 0; c < CC; ++c) {
            float qv = __shfl(qc, c, 64);
#pragma unroll
            for (int j = 0; j < 4; ++j)
                sc[j] += qv * us2f(Kls[(lane + 64 * j) * SK + c]);
        }
#pragma unroll
        for (int j = 0; j < 4; ++j) sc[j] += pm[lane + 64 * j];
        float mx = fmaxf(fmaxf(sc[0], sc[1]), fmaxf(sc[2], sc[3]));
#pragma unroll
        for (int o = 32; o > 0; o >>= 1) mx = fmaxf(mx, __shfl_xor(mx, o, 64));
        float sum = 0.f;
#pragma unroll
        for (int j = 0; j < 4; ++j) { sc[j] = __expf(sc[j] - mx); sum += sc[j]; }
#pragma unroll
        for (int o = 32; o > 0; o >>= 1) sum += __shfl_xor(sum, o, 64);
        float inv = 1.f / sum;
#pragma unroll
        for (int j = 0; j < 4; ++j) pls[w][lane + 64 * j] = sc[j] * inv;
        float acc = 0.f;
        for (int key = 0; key < 256; ++key)
            acc += pls[w][key] * us2f(Vls[key * SK + lane]);
        smix[(((size_t)bt * SS + qi) * HH + h) * CC + lane] = acc;
    }
}

// ---------------- depthwise temporal conv + residual + mean over T ----------------
__global__ __launch_bounds__(256)
void conv_mean(const float* __restrict__ smix, const float* __restrict__ cw,
               const float* __restrict__ cb, u16* __restrict__ out)
{
    int idx = blockIdx.x * 256 + threadIdx.x;
    int d = idx & 1023;
    int bs = idx >> 10;
    int b = bs >> 3, s_ = bs & 7;
    float z[TT];
#pragma unroll
    for (int t = 0; t < TT; ++t)
        z[t] = smix[((size_t)(b * TT + t) * SS + s_) * DD + d];
    float w0 = cw[d * 3], w1 = cw[d * 3 + 1], w2 = cw[d * 3 + 2];
    float acc = 0.f;
#pragma unroll
    for (int t = 0; t < TT; ++t) {
        float zc = w1 * z[t];
        if (t > 0)      zc += w0 * z[t - 1];
        if (t < TT - 1) zc += w2 * z[t + 1];
        acc += z[t] + zc;
    }
    out[(size_t)bs * DD + d] = f2us(acc * 0.125f + cb[d]);
}

// ---------------- host: launch sequence ----------------
extern "C" void kernel_launch(void* const* d_in, const int* in_sizes, int n_in,
                              void* d_out, int out_size, void* d_ws, size_t ws_size,
                              hipStream_t stream)
{
    const float* x      = (const float*)d_in[0];
    const float* s      = (const float*)d_in[1];
    const float* te     = (const float*)d_in[2];
    const float* pmask  = (const float*)d_in[3];
    const float* in_w   = (const float*)d_in[4];
    const float* in_b   = (const float*)d_in[5];
    const float* out_w  = (const float*)d_in[6];
    const float* out_b  = (const float*)d_in[7];
    const float* ln1_g  = (const float*)d_in[8];
    const float* ln1_b  = (const float*)d_in[9];
    const float* ln2_g  = (const float*)d_in[10];
    const float* ln2_b  = (const float*)d_in[11];
    const float* fc_w   = (const float*)d_in[12];
    const float* fc_b   = (const float*)d_in[13];
    const float* proj_w = (const float*)d_in[14];
    const float* proj_b = (const float*)d_in[15];
    const float* smlp_g = (const float*)d_in[16];
    const float* smlp_b = (const float*)d_in[17];
    const float* w1     = (const float*)d_in[18];
    const float* w2     = (const float*)d_in[19];
    const float* lnte_g = (const float*)d_in[20];
    const float* lnte_b = (const float*)d_in[21];
    const float* conv_w = (const float*)d_in[22];
    const float* conv_b = (const float*)d_in[23];

    float* outx = (float*)d_out;                     // [NTOK, 1024]
    float* outs = outx + (size_t)NTOK * DD;          // [64, 1024]

    char* ws = (char*)d_ws;
    u16* qkv    = (u16*)ws;                                      // [NTOK,3072] bf16
    u16* mixb   = (u16*)(ws + (size_t)NTOK * D3 * 2);            // [NTOK,1024] bf16
    u16* hidden = qkv;                                           // [NTOK,4096] overlay (exact)
    u16* xn     = (u16*)(ws + (size_t)NTOK * DFF * 2);           // [NTOK,1024] bf16
    char* sm    = ws + (size_t)NTOK * DFF * 2 + (size_t)NTOK * DD * 2;
    u16*  s_ln0 = (u16*)sm;   sm += 64 * DD * 2;
    u16*  h1    = (u16*)sm;   sm += 64 * 128 * 2;
    float* smlp = (float*)sm; sm += 64 * DD * 4;
    u16*  sn    = (u16*)sm;   sm += 64 * DD * 2;
    u16*  snqkv = (u16*)sm;   sm += 64 * D3 * 2;
    u16*  ten   = (u16*)sm;   sm += 8 * DD * 2;
    u16*  teqkv = (u16*)sm;   sm += 8 * D3 * 2;
    float* smix = (float*)sm; sm += (size_t)BB * TT * SS * DD * 4;
    u16*  smm   = (u16*)sm;   sm += 64 * DD * 2;
    u16*  ln2s  = (u16*)sm;   sm += 64 * DD * 2;
    u16*  hids  = (u16*)sm;   sm += 64 * DFF * 2;
    // bf16 weights
    u16* in_wb   = (u16*)sm;  sm += (size_t)D3 * DD * 2;
    u16* out_wb  = (u16*)sm;  sm += (size_t)DD * DD * 2;
    u16* fc_wb   = (u16*)sm;  sm += (size_t)DFF * DD * 2;
    u16* proj_wb = (u16*)sm;  sm += (size_t)DD * DFF * 2;
    u16* w1b     = (u16*)sm;  sm += (size_t)128 * DD * 2;
    u16* w2b     = (u16*)sm;  sm += (size_t)DD * 128 * 2;

    const float* FNULL = nullptr;
    u16* UNULL = nullptr;

    // 0. weight conversions
    auto cvt = [&](const float* src, u16* dst, int n) {
        hipLaunchKernelGGL(cvt_w, dim3((n / 4 + 255) / 256), dim3(256), 0, stream, src, dst, n / 4);
    };
    cvt(in_w,   in_wb,   D3 * DD);
    cvt(out_w,  out_wb,  DD * DD);
    cvt(fc_w,   fc_wb,   DFF * DD);
    cvt(proj_w, proj_wb, DD * DFF);
    cvt(w1,     w1b,     128 * DD);
    cvt(w2,     w2b,     DD * 128);

    // 1. xn = LN1(x)
    hipLaunchKernelGGL(ln_rows, dim3(NTOK), dim3(256), 0, stream, x, FNULL, ln1_g, ln1_b, xn, NTOK);
    // 2. qkv = xn @ in_proj_w^T + b
    hipLaunchKernelGGL((gemm_mfma<EPI_BF16>), dim3(D3 / 128, (NTOK + 127) / 128), dim3(256), 0, stream,
                       xn, in_wb, in_b, NTOK, D3, DD, qkv, (float*)nullptr, FNULL);
    // 3. spatial attention -> mix (MFMA flash)
    hipLaunchKernelGGL(spatial_attn, dim3(HH, BB * TT), dim3(256), 0, stream, qkv, mixb);
    // 4. outx = x + mix @ out_w^T + out_b
    hipLaunchKernelGGL((gemm_mfma<EPI_RES>), dim3(DD / 128, (NTOK + 127) / 128), dim3(256), 0, stream,
                       mixb, out_wb, out_b, NTOK, DD, DD, UNULL, outx, x);
    // 5. syno-token branch
    hipLaunchKernelGGL(ln_rows, dim3(64), dim3(256), 0, stream, s, FNULL, smlp_g, smlp_b, s_ln0, 64);
    hipLaunchKernelGGL((gemm_mfma<EPI_BF16>), dim3(1, 1), dim3(256), 0, stream,
                       s_ln0, w1b, FNULL, 64, 128, DD, h1, (float*)nullptr, FNULL);
    hipLaunchKernelGGL((gemm_mfma<EPI_F32>), dim3(DD / 128, 1), dim3(256), 0, stream,
                       h1, w2b, FNULL, 64, DD, 128, UNULL, smlp, FNULL);
    hipLaunchKernelGGL(ln_rows, dim3(64), dim3(256), 0, stream, s, smlp, ln1_g, ln1_b, sn, 64);
    hipLaunchKernelGGL(ln_te, dim3(1), dim3(256), 0, stream, te, lnte_g, lnte_b, ten);
    hipLaunchKernelGGL((gemm_mfma<EPI_BF16>), dim3(D3 / 128, 1), dim3(256), 0, stream,
                       sn, in_wb, in_b, 64, D3, DD, snqkv, (float*)nullptr, FNULL);
    hipLaunchKernelGGL((gemm_mfma<EPI_BF16>), dim3(D3 / 128, 1), dim3(256), 0, stream,
                       ten, in_wb, in_b, 8, D3, DD, teqkv, (float*)nullptr, FNULL);
    hipLaunchKernelGGL(s_attn, dim3(HH, BB * TT), dim3(256), 0, stream, qkv, snqkv, teqkv, pmask, smix);
    hipLaunchKernelGGL(conv_mean, dim3(256), dim3(256), 0, stream, smix, conv_w, conv_b, smm);
    hipLaunchKernelGGL((gemm_mfma<EPI_RES>), dim3(DD / 128, 1), dim3(256), 0, stream,
                       smm, out_wb, out_b, 64, DD, DD, UNULL, outs, s);
    // 6. x MLP: outx += proj(gelu(fc(LN2(outx))))
    hipLaunchKernelGGL(ln_rows, dim3(NTOK), dim3(256), 0, stream, outx, FNULL, ln2_g, ln2_b, xn, NTOK);
    hipLaunchKernelGGL((gemm_mfma<EPI_GELU>), dim3(DFF / 128, (NTOK + 127) / 128), dim3(256), 0, stream,
                       xn, fc_wb, fc_b, NTOK, DFF, DD, hidden, (float*)nullptr, FNULL);
    hipLaunchKernelGGL((gemm_mfma<EPI_RES>), dim3(DD / 128, (NTOK + 127) / 128), dim3(256), 0, stream,
                       hidden, proj_wb, proj_b, NTOK, DD, DFF, UNULL, outx, outx);
    // 7. s MLP
    hipLaunchKernelGGL(ln_rows, dim3(64), dim3(256), 0, stream, outs, FNULL, ln2_g, ln2_b, ln2s, 64);
    hipLaunchKernelGGL((gemm_mfma<EPI_GELU>), dim3(DFF / 128, 1), dim3(256), 0, stream,
                       ln2s, fc_wb, fc_b, 64, DFF, DD, hids, (float*)nullptr, FNULL);
    hipLaunchKernelGGL((gemm_mfma<EPI_RES>), dim3(DD / 128, 1), dim3(256), 0, stream,
                       hids, proj_wb, proj_b, 64, DD, DFF, UNULL, outs, outs);
}

// Round 5
// 1667.746 us; speedup vs baseline: 6.6516x; 1.0403x over previous
//
#include <hip/hip_runtime.h>
#include <hip/hip_bf16.h>

// ---------------- problem constants ----------------
#define BB 8
#define TT 8
#define LL 257
#define DD 1024
#define HH 16
#define CC 64
#define SS 8
#define NTOK (BB*TT*LL)   // 16448
#define D3 (3*DD)         // 3072
#define DFF (4*DD)        // 4096

typedef unsigned short u16;   // bf16 bits
typedef __attribute__((ext_vector_type(8))) short short8;
typedef __attribute__((ext_vector_type(4))) short short4v;
typedef __attribute__((ext_vector_type(4))) float f32x4;

__device__ __forceinline__ float us2f(u16 u) {
    return __uint_as_float(((unsigned int)u) << 16);
}
__device__ __forceinline__ u16 f2us(float f) {
    unsigned int u = __float_as_uint(f);
    unsigned int rb = ((u >> 16) & 1u) + 0x7fffu;   // round-to-nearest-even
    return (u16)((u + rb) >> 16);
}

__device__ __forceinline__ void gload_lds16(const u16* g, u16* l) {
    __builtin_amdgcn_global_load_lds(
        (__attribute__((address_space(1))) void*)(void*)g,
        (__attribute__((address_space(3))) void*)(void*)l, 16, 0, 0);
}

// ---------------- fp32 -> bf16 weight conversion ----------------
__global__ __launch_bounds__(256)
void cvt_w(const float* __restrict__ in, u16* __restrict__ out, int n4)
{
    int i = blockIdx.x * 256 + threadIdx.x;
    if (i >= n4) return;
    float4 v = reinterpret_cast<const float4*>(in)[i];
    ushort4 o;
    o.x = f2us(v.x); o.y = f2us(v.y); o.z = f2us(v.z); o.w = f2us(v.w);
    reinterpret_cast<ushort4*>(out)[i] = o;
}

// ---------------- LayerNorm over last dim (1024), optional residual add ----------------
__global__ __launch_bounds__(256)
void ln_rows(const float* __restrict__ X, const float* __restrict__ R,
             const float* __restrict__ g, const float* __restrict__ bta,
             u16* __restrict__ out, int M)
{
    int row = blockIdx.x;
    if (row >= M) return;
    const float* x = X + (size_t)row * DD;
    const float* r = R ? R + (size_t)row * DD : nullptr;
    int t = threadIdx.x;
    float v[4]; float s1 = 0.f, s2 = 0.f;
#pragma unroll
    for (int i = 0; i < 4; ++i) {
        float val = x[t + 256 * i];
        if (r) val += r[t + 256 * i];
        v[i] = val; s1 += val; s2 += val * val;
    }
#pragma unroll
    for (int o = 32; o > 0; o >>= 1) { s1 += __shfl_xor(s1, o, 64); s2 += __shfl_xor(s2, o, 64); }
    __shared__ float red[10];
    int wid = t >> 6, lane = t & 63;
    if (lane == 0) { red[wid] = s1; red[4 + wid] = s2; }
    __syncthreads();
    if (t == 0) {
        float a = red[0] + red[1] + red[2] + red[3];
        float q = red[4] + red[5] + red[6] + red[7];
        float mu = a * (1.f / DD);
        float var = q * (1.f / DD) - mu * mu;
        red[8] = mu; red[9] = rsqrtf(var + 1e-5f);
    }
    __syncthreads();
    float mu = red[8], rs = red[9];
#pragma unroll
    for (int i = 0; i < 4; ++i) {
        int c = t + 256 * i;
        out[(size_t)row * DD + c] = f2us((v[i] - mu) * rs * g[c] + bta[c]);
    }
}

// ---------------- LayerNorm over whole (T,D) tensor (te) ----------------
__global__ __launch_bounds__(256)
void ln_te(const float* __restrict__ te, const float* __restrict__ g,
           const float* __restrict__ bta, u16* __restrict__ out)
{
    const int NE = TT * DD;   // 8192
    int t = threadIdx.x;
    float s1 = 0.f, s2 = 0.f;
    for (int i = t; i < NE; i += 256) { float v = te[i]; s1 += v; s2 += v * v; }
#pragma unroll
    for (int o = 32; o > 0; o >>= 1) { s1 += __shfl_xor(s1, o, 64); s2 += __shfl_xor(s2, o, 64); }
    __shared__ float red[10];
    int wid = t >> 6, lane = t & 63;
    if (lane == 0) { red[wid] = s1; red[4 + wid] = s2; }
    __syncthreads();
    if (t == 0) {
        float a = red[0] + red[1] + red[2] + red[3];
        float q = red[4] + red[5] + red[6] + red[7];
        float mu = a / (float)NE;
        float var = q / (float)NE - mu * mu;
        red[8] = mu; red[9] = rsqrtf(var + 1e-5f);
    }
    __syncthreads();
    float mu = red[8], rs = red[9];
    for (int i = t; i < NE; i += 256)
        out[i] = f2us((te[i] - mu) * rs * g[i] + bta[i]);
}

// ---------------- MFMA GEMM: C[m,j] = sum_k A[m,k]*W[j,k] (+bias) ----------------
// T1 XCD swizzle + T3 minimum 2-phase double-buffer:
//   prologue: STAGE(buf0, t=0); barrier;
//   loop t:   STAGE(buf[cur^1], t+1); ds_read buf[cur]; MFMA; barrier; cur^=1;
// The barrier's vmcnt(0) drain lands AFTER ~200cy of ds_read+MFMA instead of
// right after load issue -> staging latency hidden (catalog T3, m228d 622 TF).
enum { EPI_BF16 = 0, EPI_GELU = 1, EPI_RES = 2, EPI_F32 = 3 };

template<int EPI>
__global__ __launch_bounds__(256)
void gemm_mfma(const u16* __restrict__ A, const u16* __restrict__ W,
               const float* __restrict__ bias, int M, int N, int K,
               u16* __restrict__ outB, float* __restrict__ outF,
               const float* __restrict__ res)
{
    __shared__ u16 Als[2][128 * 32];
    __shared__ u16 Bls[2][128 * 32];
    const int tid = threadIdx.x;
    const int lane = tid & 63;
    const int wid = tid >> 6;
    const int wm = (wid >> 1) * 64, wn = (wid & 1) * 64;

    // XCD-chunked bijective swizzle
    const int gx = gridDim.x;
    const int nwg = gx * gridDim.y;
    int bid = blockIdx.y * gx + blockIdx.x;
    int qq = nwg >> 3, rr = nwg & 7;
    int xcd = bid & 7, idx = bid >> 3;
    int nb = (xcd < rr ? xcd * (qq + 1) : rr * (qq + 1) + (xcd - rr) * qq) + idx;
    const int m0 = (nb / gx) * 128, n0 = (nb % gx) * 128;

    int o0 = tid, o1 = tid + 256;
    int g0 = o0 >> 6, kb0 = (o0 >> 4) & 3, r0 = o0 & 15;
    int g1 = o1 >> 6, kb1 = (o1 >> 4) & 3, r1 = o1 & 15;
    int ar0 = m0 + g0 * 16 + r0; if (ar0 >= M) ar0 = M - 1;
    int ar1 = m0 + g1 * 16 + r1; if (ar1 >= M) ar1 = M - 1;
    int br0 = n0 + g0 * 16 + r0;
    int br1 = n0 + g1 * 16 + r1;
    const u16* a0 = A + (size_t)ar0 * K + kb0 * 8;
    const u16* a1 = A + (size_t)ar1 * K + kb1 * 8;
    const u16* b0 = W + (size_t)br0 * K + kb0 * 8;
    const u16* b1 = W + (size_t)br1 * K + kb1 * 8;

    f32x4 acc[4][4];
#pragma unroll
    for (int i = 0; i < 4; ++i)
#pragma unroll
        for (int j = 0; j < 4; ++j)
            acc[i][j] = (f32x4){0.f, 0.f, 0.f, 0.f};

    // prologue: stage tile 0
    gload_lds16(a0, &Als[0][o0 * 8]);
    gload_lds16(a1, &Als[0][o1 * 8]);
    gload_lds16(b0, &Bls[0][o0 * 8]);
    gload_lds16(b1, &Bls[0][o1 * 8]);
    __syncthreads();

    const int nk = K >> 5;
    int cur = 0;
    for (int t = 0; t < nk; ++t) {
        if (t + 1 < nk) {
            int k1 = (t + 1) << 5;
            gload_lds16(a0 + k1, &Als[cur ^ 1][o0 * 8]);
            gload_lds16(a1 + k1, &Als[cur ^ 1][o1 * 8]);
            gload_lds16(b0 + k1, &Bls[cur ^ 1][o0 * 8]);
            gload_lds16(b1 + k1, &Bls[cur ^ 1][o1 * 8]);
        }
        short8 af[4], bfr[4];
#pragma unroll
        for (int i = 0; i < 4; ++i)
            af[i] = *reinterpret_cast<const short8*>(&Als[cur][((wm >> 4) + i) * 512 + lane * 8]);
#pragma unroll
        for (int j = 0; j < 4; ++j)
            bfr[j] = *reinterpret_cast<const short8*>(&Bls[cur][((wn >> 4) + j) * 512 + lane * 8]);
        __builtin_amdgcn_s_setprio(1);
#pragma unroll
        for (int i = 0; i < 4; ++i)
#pragma unroll
            for (int j = 0; j < 4; ++j)
                acc[i][j] = __builtin_amdgcn_mfma_f32_16x16x32_bf16(af[i], bfr[j], acc[i][j], 0, 0, 0);
        __builtin_amdgcn_s_setprio(0);
        __syncthreads();   // drains vmcnt(0) (next tile staged) + lgkmcnt
        cur ^= 1;
    }

    const int cn = lane & 15, cr = (lane >> 4) * 4;
#pragma unroll
    for (int i = 0; i < 4; ++i) {
#pragma unroll
        for (int r = 0; r < 4; ++r) {
            int m = m0 + wm + i * 16 + cr + r;
            if (m >= M) continue;
#pragma unroll
            for (int j = 0; j < 4; ++j) {
                int n = n0 + wn + j * 16 + cn;
                float c = acc[i][j][r];
                if (bias) c += bias[n];
                size_t o = (size_t)m * N + n;
                if (EPI == EPI_BF16) outB[o] = f2us(c);
                else if (EPI == EPI_GELU) { float gg = c / (1.f + __expf(-1.702f * c)); outB[o] = f2us(gg); }
                else if (EPI == EPI_RES) outF[o] = res[o] + c;
                else outF[o] = c;
            }
        }
    }
}

// ---------------- MFMA spatial attention: one block (4 waves) per (h, b*t) ----------------
#define KSTR 72
#define VSTR 296
#define PSTR 40

__global__ __launch_bounds__(256)
void spatial_attn(const u16* __restrict__ qkv, u16* __restrict__ mix)
{
    const int h = blockIdx.x, bt = blockIdx.y;
    const int hoff = h * CC;
    const size_t base = (size_t)bt * LL * D3;
    __shared__ u16 Kls[257 * KSTR];
    __shared__ u16 Vt[64 * VSTR];
    __shared__ u16 Pb[4][16 * PSTR];
    const int tid = threadIdx.x, lane = tid & 63, w = tid >> 6;
    const int c15 = lane & 15, g = lane >> 4;

    for (int idx = tid; idx < 257 * 8; idx += 256) {
        int row = idx >> 3, c8 = (idx & 7) << 3;
        float4 v = *reinterpret_cast<const float4*>(&qkv[base + (size_t)row * D3 + DD + hoff + c8]);
        *reinterpret_cast<float4*>(&Kls[row * KSTR + c8]) = v;
    }
    for (int idx = tid; idx < 288 * 64; idx += 256) {
        int key = idx >> 6, c = idx & 63;
        u16 v = 0;
        if (key < 257) v = qkv[base + (size_t)key * D3 + 2 * DD + hoff + c];
        Vt[c * VSTR + key] = v;
    }
    __syncthreads();

    u16* pb = Pb[w];
    for (int qt = w; qt < 17; qt += 4) {
        int qrow = qt * 16 + c15; if (qrow > 256) qrow = 256;
        const u16* qp = &qkv[base + (size_t)qrow * D3 + hoff + g * 8];
        short8 a0 = *reinterpret_cast<const short8*>(qp);
        short8 a1 = *reinterpret_cast<const short8*>(qp + 32);

        f32x4 sc[17];
#pragma unroll
        for (int t = 0; t < 17; ++t) sc[t] = (f32x4){0.f, 0.f, 0.f, 0.f};
        __builtin_amdgcn_s_setprio(1);
#pragma unroll
        for (int t = 0; t < 17; ++t) {
            int krow = t * 16 + c15; if (krow > 256) krow = 256;
            short8 b0 = *reinterpret_cast<const short8*>(&Kls[krow * KSTR + g * 8]);
            short8 b1 = *reinterpret_cast<const short8*>(&Kls[krow * KSTR + 32 + g * 8]);
            sc[t] = __builtin_amdgcn_mfma_f32_16x16x32_bf16(a0, b0, sc[t], 0, 0, 0);
            sc[t] = __builtin_amdgcn_mfma_f32_16x16x32_bf16(a1, b1, sc[t], 0, 0, 0);
        }
        __builtin_amdgcn_s_setprio(0);

        const bool lastv = (c15 == 0);
#pragma unroll
        for (int r = 0; r < 4; ++r) {
            float mx = -1e30f;
#pragma unroll
            for (int t = 0; t < 17; ++t) {
                float v = sc[t][r] * 0.125f;
                if (t == 16 && !lastv) v = -1e30f;
                sc[t][r] = v;
                mx = fmaxf(mx, v);
            }
            mx = fmaxf(mx, __shfl_xor(mx, 1, 64));
            mx = fmaxf(mx, __shfl_xor(mx, 2, 64));
            mx = fmaxf(mx, __shfl_xor(mx, 4, 64));
            mx = fmaxf(mx, __shfl_xor(mx, 8, 64));
            float sum = 0.f;
#pragma unroll
            for (int t = 0; t < 17; ++t) { float e = __expf(sc[t][r] - mx); sc[t][r] = e; sum += e; }
            sum += __shfl_xor(sum, 1, 64);
            sum += __shfl_xor(sum, 2, 64);
            sum += __shfl_xor(sum, 4, 64);
            sum += __shfl_xor(sum, 8, 64);
            float is = 1.f / sum;
#pragma unroll
            for (int t = 0; t < 17; ++t) sc[t][r] *= is;
        }

        f32x4 oacc[4];
#pragma unroll
        for (int ct = 0; ct < 4; ++ct) oacc[ct] = (f32x4){0.f, 0.f, 0.f, 0.f};
#pragma unroll
        for (int k0 = 0; k0 < 9; ++k0) {
            const int t0 = 2 * k0, t1 = 2 * k0 + 1;
#pragma unroll
            for (int r = 0; r < 4; ++r) {
                pb[(4 * g + r) * PSTR + c15]      = f2us(sc[t0][r]);
                pb[(4 * g + r) * PSTR + 16 + c15] = (t1 < 17) ? f2us(sc[t1][r]) : (u16)0;
            }
            short8 pa = *reinterpret_cast<const short8*>(&pb[c15 * PSTR + 8 * g]);
            __builtin_amdgcn_s_setprio(1);
#pragma unroll
            for (int ct = 0; ct < 4; ++ct) {
                short8 vb = *reinterpret_cast<const short8*>(&Vt[(16 * ct + c15) * VSTR + 32 * k0 + 8 * g]);
                oacc[ct] = __builtin_amdgcn_mfma_f32_16x16x32_bf16(pa, vb, oacc[ct], 0, 0, 0);
            }
            __builtin_amdgcn_s_setprio(0);
        }

#pragma unroll
        for (int r = 0; r < 4; ++r) {
            int q = qt * 16 + 4 * g + r;
            if (q >= LL) continue;
            size_t ob = ((size_t)bt * LL + q) * DD + hoff;
#pragma unroll
            for (int ct = 0; ct < 4; ++ct)
                mix[ob + 16 * ct + c15] = f2us(oacc[ct][r]);
        }
    }
}

// ---------------- syno-token attention: one block (4 waves) per (h, b*t) ----------------
#define SK 68

__global__ __launch_bounds__(256)
void s_attn(const u16* __restrict__ qkv, const u16* __restrict__ snqkv,
            const u16* __restrict__ teqkv, const float* __restrict__ pmask,
            float* __restrict__ smix)
{
    const int h = blockIdx.x, bt = blockIdx.y, b = bt >> 3, t = bt & 7;
    const int hoff = h * CC;
    const int tid = threadIdx.x, lane = tid & 63, w = tid >> 6;
    __shared__ u16 Kls[256 * SK];
    __shared__ u16 Vls[256 * SK];
    __shared__ float pls[4][256];
    const size_t base = (size_t)bt * LL * D3;

    const int c8 = (tid & 7) * 8;
    const u16* tekp = &teqkv[t * D3 + DD + hoff + c8];
    const u16* tevp = &teqkv[t * D3 + 2 * DD + hoff + c8];
    float tek[8], tev[8];
#pragma unroll
    for (int j = 0; j < 8; ++j) { tek[j] = us2f(tekp[j]); tev[j] = us2f(tevp[j]); }
#pragma unroll
    for (int pass = 0; pass < 8; ++pass) {
        int key = (tid >> 3) + 32 * pass;
        const u16* kp = &qkv[base + (size_t)(key + 1) * D3 + DD + hoff + c8];
        const u16* vp = &qkv[base + (size_t)(key + 1) * D3 + 2 * DD + hoff + c8];
        short4v k0 = *reinterpret_cast<const short4v*>(kp);
        short4v k1 = *reinterpret_cast<const short4v*>(kp + 4);
        short4v v0 = *reinterpret_cast<const short4v*>(vp);
        short4v v1 = *reinterpret_cast<const short4v*>(vp + 4);
        short4v ok0, ok1, ov0, ov1;
#pragma unroll
        for (int j = 0; j < 4; ++j) {
            ok0[j] = (short)f2us(us2f((u16)k0[j]) + tek[j]);
            ok1[j] = (short)f2us(us2f((u16)k1[j]) + tek[4 + j]);
            ov0[j] = (short)f2us(us2f((u16)v0[j]) + tev[j]);
            ov1[j] = (short)f2us(us2f((u16)v1[j]) + tev[4 + j]);
        }
        *reinterpret_cast<short4v*>(&Kls[key * SK + c8]) = ok0;
        *reinterpret_cast<short4v*>(&Kls[key * SK + c8 + 4]) = ok1;
        *reinterpret_cast<short4v*>(&Vls[key * SK + c8]) = ov0;
        *reinterpret_cast<short4v*>(&Vls[key * SK + c8 + 4]) = ov1;
    }
    __syncthreads();

    const float* pm = pmask + (size_t)bt * 256;
    for (int qi = w; qi < SS; qi += 4) {
        float qc = us2f(snqkv[(size_t)(b * SS + qi) * D3 + hoff + lane]) * 0.125f;
        float sc[4] = {0.f, 0.f, 0.f, 0.f};
        for (int c = 0; c < CC; ++c) {
            float qv = __shfl(qc, c, 64);
#pragma unroll
            for (int j = 0; j < 4; ++j)
                sc[j] += qv * us2f(Kls[(lane + 64 * j) * SK + c]);
        }
#pragma unroll
        for (int j = 0; j < 4; ++j) sc[j] += pm[lane + 64 * j];
        float mx = fmaxf(fmaxf(sc[0], sc[1]), fmaxf(sc[2], sc[3]));
#pragma unroll
        for (int o = 32; o > 0; o >>= 1) mx = fmaxf(mx, __shfl_xor(mx, o, 64));
        float sum = 0.f;
#pragma unroll
        for (int j = 0; j < 4; ++j) { sc[j] = __expf(sc[j] - mx); sum += sc[j]; }
#pragma unroll
        for (int o = 32; o > 0; o >>= 1) sum += __shfl_xor(sum, o, 64);
        float inv = 1.f / sum;
#pragma unroll
        for (int j = 0; j < 4; ++j) pls[w][lane + 64 * j] = sc[j] * inv;
        float acc = 0.f;
        for (int key = 0; key < 256; ++key)
            acc += pls[w][key] * us2f(Vls[key * SK + lane]);
        smix[(((size_t)bt * SS + qi) * HH + h) * CC + lane] = acc;
    }
}

// ---------------- depthwise temporal conv + residual + mean over T ----------------
__global__ __launch_bounds__(256)
void conv_mean(const float* __restrict__ smix, const float* __restrict__ cw,
               const float* __restrict__ cb, u16* __restrict__ out)
{
    int idx = blockIdx.x * 256 + threadIdx.x;
    int d = idx & 1023;
    int bs = idx >> 10;
    int b = bs >> 3, s_ = bs & 7;
    float z[TT];
#pragma unroll
    for (int t = 0; t < TT; ++t)
        z[t] = smix[((size_t)(b * TT + t) * SS + s_) * DD + d];
    float w0 = cw[d * 3], w1 = cw[d * 3 + 1], w2 = cw[d * 3 + 2];
    float acc = 0.f;
#pragma unroll
    for (int t = 0; t < TT; ++t) {
        float zc = w1 * z[t];
        if (t > 0)      zc += w0 * z[t - 1];
        if (t < TT - 1) zc += w2 * z[t + 1];
        acc += z[t] + zc;
    }
    out[(size_t)bs * DD + d] = f2us(acc * 0.125f + cb[d]);
}

// ---------------- host: launch sequence ----------------
extern "C" void kernel_launch(void* const* d_in, const int* in_sizes, int n_in,
                              void* d_out, int out_size, void* d_ws, size_t ws_size,
                              hipStream_t stream)
{
    const float* x      = (const float*)d_in[0];
    const float* s      = (const float*)d_in[1];
    const float* te     = (const float*)d_in[2];
    const float* pmask  = (const float*)d_in[3];
    const float* in_w   = (const float*)d_in[4];
    const float* in_b   = (const float*)d_in[5];
    const float* out_w  = (const float*)d_in[6];
    const float* out_b  = (const float*)d_in[7];
    const float* ln1_g  = (const float*)d_in[8];
    const float* ln1_b  = (const float*)d_in[9];
    const float* ln2_g  = (const float*)d_in[10];
    const float* ln2_b  = (const float*)d_in[11];
    const float* fc_w   = (const float*)d_in[12];
    const float* fc_b   = (const float*)d_in[13];
    const float* proj_w = (const float*)d_in[14];
    const float* proj_b = (const float*)d_in[15];
    const float* smlp_g = (const float*)d_in[16];
    const float* smlp_b = (const float*)d_in[17];
    const float* w1     = (const float*)d_in[18];
    const float* w2     = (const float*)d_in[19];
    const float* lnte_g = (const float*)d_in[20];
    const float* lnte_b = (const float*)d_in[21];
    const float* conv_w = (const float*)d_in[22];
    const float* conv_b = (const float*)d_in[23];

    float* outx = (float*)d_out;                     // [NTOK, 1024]
    float* outs = outx + (size_t)NTOK * DD;          // [64, 1024]

    char* ws = (char*)d_ws;
    u16* qkv    = (u16*)ws;                                      // [NTOK,3072] bf16
    u16* mixb   = (u16*)(ws + (size_t)NTOK * D3 * 2);            // [NTOK,1024] bf16
    u16* hidden = qkv;                                           // [NTOK,4096] overlay (exact)
    u16* xn     = (u16*)(ws + (size_t)NTOK * DFF * 2);           // [NTOK,1024] bf16
    char* sm    = ws + (size_t)NTOK * DFF * 2 + (size_t)NTOK * DD * 2;
    u16*  s_ln0 = (u16*)sm;   sm += 64 * DD * 2;
    u16*  h1    = (u16*)sm;   sm += 64 * 128 * 2;
    float* smlp = (float*)sm; sm += 64 * DD * 4;
    u16*  sn    = (u16*)sm;   sm += 64 * DD * 2;
    u16*  snqkv = (u16*)sm;   sm += 64 * D3 * 2;
    u16*  ten   = (u16*)sm;   sm += 8 * DD * 2;
    u16*  teqkv = (u16*)sm;   sm += 8 * D3 * 2;
    float* smix = (float*)sm; sm += (size_t)BB * TT * SS * DD * 4;
    u16*  smm   = (u16*)sm;   sm += 64 * DD * 2;
    u16*  ln2s  = (u16*)sm;   sm += 64 * DD * 2;
    u16*  hids  = (u16*)sm;   sm += 64 * DFF * 2;
    // bf16 weights
    u16* in_wb   = (u16*)sm;  sm += (size_t)D3 * DD * 2;
    u16* out_wb  = (u16*)sm;  sm += (size_t)DD * DD * 2;
    u16* fc_wb   = (u16*)sm;  sm += (size_t)DFF * DD * 2;
    u16* proj_wb = (u16*)sm;  sm += (size_t)DD * DFF * 2;
    u16* w1b     = (u16*)sm;  sm += (size_t)128 * DD * 2;
    u16* w2b     = (u16*)sm;  sm += (size_t)DD * 128 * 2;

    const float* FNULL = nullptr;
    u16* UNULL = nullptr;

    // 0. weight conversions
    auto cvt = [&](const float* src, u16* dst, int n) {
        hipLaunchKernelGGL(cvt_w, dim3((n / 4 + 255) / 256), dim3(256), 0, stream, src, dst, n / 4);
    };
    cvt(in_w,   in_wb,   D3 * DD);
    cvt(out_w,  out_wb,  DD * DD);
    cvt(fc_w,   fc_wb,   DFF * DD);
    cvt(proj_w, proj_wb, DD * DFF);
    cvt(w1,     w1b,     128 * DD);
    cvt(w2,     w2b,     DD * 128);

    // 1. xn = LN1(x)
    hipLaunchKernelGGL(ln_rows, dim3(NTOK), dim3(256), 0, stream, x, FNULL, ln1_g, ln1_b, xn, NTOK);
    // 2. qkv = xn @ in_proj_w^T + b
    hipLaunchKernelGGL((gemm_mfma<EPI_BF16>), dim3(D3 / 128, (NTOK + 127) / 128), dim3(256), 0, stream,
                       xn, in_wb, in_b, NTOK, D3, DD, qkv, (float*)nullptr, FNULL);
    // 3. spatial attention -> mix (MFMA flash)
    hipLaunchKernelGGL(spatial_attn, dim3(HH, BB * TT), dim3(256), 0, stream, qkv, mixb);
    // 4. outx = x + mix @ out_w^T + out_b
    hipLaunchKernelGGL((gemm_mfma<EPI_RES>), dim3(DD / 128, (NTOK + 127) / 128), dim3(256), 0, stream,
                       mixb, out_wb, out_b, NTOK, DD, DD, UNULL, outx, x);
    // 5. syno-token branch
    hipLaunchKernelGGL(ln_rows, dim3(64), dim3(256), 0, stream, s, FNULL, smlp_g, smlp_b, s_ln0, 64);
    hipLaunchKernelGGL((gemm_mfma<EPI_BF16>), dim3(1, 1), dim3(256), 0, stream,
                       s_ln0, w1b, FNULL, 64, 128, DD, h1, (float*)nullptr, FNULL);
    hipLaunchKernelGGL((gemm_mfma<EPI_F32>), dim3(DD / 128, 1), dim3(256), 0, stream,
                       h1, w2b, FNULL, 64, DD, 128, UNULL, smlp, FNULL);
    hipLaunchKernelGGL(ln_rows, dim3(64), dim3(256), 0, stream, s, smlp, ln1_g, ln1_b, sn, 64);
    hipLaunchKernelGGL(ln_te, dim3(1), dim3(256), 0, stream, te, lnte_g, lnte_b, ten);
    hipLaunchKernelGGL((gemm_mfma<EPI_BF16>), dim3(D3 / 128, 1), dim3(256), 0, stream,
                       sn, in_wb, in_b, 64, D3, DD, snqkv, (float*)nullptr, FNULL);
    hipLaunchKernelGGL((gemm_mfma<EPI_BF16>), dim3(D3 / 128, 1), dim3(256), 0, stream,
                       ten, in_wb, in_b, 8, D3, DD, teqkv, (float*)nullptr, FNULL);
    hipLaunchKernelGGL(s_attn, dim3(HH, BB * TT), dim3(256), 0, stream, qkv, snqkv, teqkv, pmask, smix);
    hipLaunchKernelGGL(conv_mean, dim3(256), dim3(256), 0, stream, smix, conv_w, conv_b, smm);
    hipLaunchKernelGGL((gemm_mfma<EPI_RES>), dim3(DD / 128, 1), dim3(256), 0, stream,
                       smm, out_wb, out_b, 64, DD, DD, UNULL, outs, s);
    // 6. x MLP: outx += proj(gelu(fc(LN2(outx))))
    hipLaunchKernelGGL(ln_rows, dim3(NTOK), dim3(256), 0, stream, outx, FNULL, ln2_g, ln2_b, xn, NTOK);
    hipLaunchKernelGGL((gemm_mfma<EPI_GELU>), dim3(DFF / 128, (NTOK + 127) / 128), dim3(256), 0, stream,
                       xn, fc_wb, fc_b, NTOK, DFF, DD, hidden, (float*)nullptr, FNULL);
    hipLaunchKernelGGL((gemm_mfma<EPI_RES>), dim3(DD / 128, (NTOK + 127) / 128), dim3(256), 0, stream,
                       hidden, proj_wb, proj_b, NTOK, DD, DFF, UNULL, outx, outx);
    // 7. s MLP
    hipLaunchKernelGGL(ln_rows, dim3(64), dim3(256), 0, stream, outs, FNULL, ln2_g, ln2_b, ln2s, 64);
    hipLaunchKernelGGL((gemm_mfma<EPI_GELU>), dim3(DFF / 128, 1), dim3(256), 0, stream,
                       ln2s, fc_wb, fc_b, 64, DFF, DD, hids, (float*)nullptr, FNULL);
    hipLaunchKernelGGL((gemm_mfma<EPI_RES>), dim3(DD / 128, 1), dim3(256), 0, stream,
                       hids, proj_wb, proj_b, 64, DD, DFF, UNULL, outs, outs);
}